// Round 14
// baseline (989.424 us; speedup 1.0000x reference)
//
#include <hip/hip_runtime.h>
#include <hip/hip_bf16.h>
#include <math.h>

#define DIMX 2048
#define SLEN 2048
#define BSZ 2
#define NHEADS 16
#define HDIM 128
#define FFND 8192
#define CTXL 512
#define LN_EPS 1e-6f

typedef __attribute__((ext_vector_type(8))) short short8_t;
typedef __attribute__((ext_vector_type(4))) short short4_t;
typedef __attribute__((ext_vector_type(4))) float f32x4;
typedef __hip_bfloat16 bf16;

__device__ __forceinline__ short f2bf(float f) {
  union { float f; unsigned u; } v; v.f = f;
  return (short)((v.u + 0x7FFFu + ((v.u >> 16) & 1u)) >> 16);
}
__device__ __forceinline__ float bf2f(short s) {
  union { unsigned u; float f; } v; v.u = ((unsigned)(unsigned short)s) << 16;
  return v.f;
}

__device__ __forceinline__ void gload16(const void* g, void* l) {
  __builtin_amdgcn_global_load_lds(
      (const __attribute__((address_space(1))) unsigned int*)g,
      (__attribute__((address_space(3))) unsigned int*)l, 16, 0, 0);
}

__device__ __forceinline__ float wred_sum(float v) {
#pragma unroll
  for (int o = 32; o > 0; o >>= 1) v += __shfl_xor(v, o, 64);
  return v;
}

// fused: em add + bias packs (qkv: 3D, ckv: 2D) + context fp32->bf16
__global__ void prep_kernel(const float* __restrict__ e, const float* __restrict__ mod,
                            float* __restrict__ em,
                            const float* __restrict__ sa_bq, const float* __restrict__ sa_bk,
                            const float* __restrict__ sa_bv, float* __restrict__ bqkv,
                            const float* __restrict__ ca_bk, const float* __restrict__ ca_bv,
                            float* __restrict__ bckv,
                            const float* __restrict__ ctx, bf16* __restrict__ ctxb) {
  int i = blockIdx.x * 256 + threadIdx.x;
  if (i < BSZ * 6 * DIMX) { em[i] = e[i] + mod[i % (6 * DIMX)]; return; }
  i -= BSZ * 6 * DIMX;
  if (i < 3 * DIMX) {
    bqkv[i] = (i < DIMX) ? sa_bq[i] : (i < 2 * DIMX) ? sa_bk[i - DIMX] : sa_bv[i - 2 * DIMX];
    return;
  }
  i -= 3 * DIMX;
  if (i < 2 * DIMX) { bckv[i] = (i < DIMX) ? ca_bk[i] : ca_bv[i - DIMX]; return; }
  i -= 2 * DIMX;
  if (i < BSZ * CTXL * DIMX / 8) {
    float4 a = *(const float4*)(ctx + (size_t)i * 8);
    float4 b = *(const float4*)(ctx + (size_t)i * 8 + 4);
    float fv[8] = {a.x, a.y, a.z, a.w, b.x, b.y, b.z, b.w};
    short8_t o;
#pragma unroll
    for (int j = 0; j < 8; ++j) o[j] = f2bf(fv[j]);
    *(short8_t*)((short*)ctxb + (size_t)i * 8) = o;
  }
}

// out = resid + (p0 + p1 + bias) * scale   (FFN2 split-K combine)
__global__ __launch_bounds__(256) void combine_kernel(
    const bf16* __restrict__ p0, const bf16* __restrict__ p1,
    const float* __restrict__ bias, const float* __restrict__ resid,
    const float* __restrict__ scale, int scstride, int rows_per_b,
    float* __restrict__ out, int N) {
  int i8 = blockIdx.x * 256 + threadIdx.x;
  size_t base = (size_t)i8 * 8;
  int n = (int)(base % N);
  int m = (int)(base / N);
  int b = m / rows_per_b;
  short8_t a = *(const short8_t*)((const short*)p0 + base);
  short8_t c = *(const short8_t*)((const short*)p1 + base);
  const float* bi = bias + n;
  const float* sc = scale + (size_t)b * scstride + n;
  const float* rs = resid + base;
  float* o = out + base;
#pragma unroll
  for (int j = 0; j < 8; ++j)
    o[j] = rs[j] + (bf2f(a[j]) + bf2f(c[j]) + bi[j]) * sc[j];
}

// batched: up to 4 weights [K][N] -> Wt bf16 rows [z*N + n][K]
__global__ __launch_bounds__(256) void transpose_w4(
    const float* s0, const float* s1, const float* s2, const float* s3,
    bf16* __restrict__ Wt, int K, int N) {
  __shared__ short tile[64 * 68];
  const float* W = (blockIdx.z == 0) ? s0 : (blockIdx.z == 1) ? s1
                   : (blockIdx.z == 2) ? s2 : s3;
  int noff = blockIdx.z * N;
  int k0 = blockIdx.y << 6, n0 = blockIdx.x << 6;
  int t = threadIdx.x;
#pragma unroll
  for (int p = 0; p < 4; ++p) {
    int lin = p * 1024 + t * 4;
    int kr = lin >> 6, nc = lin & 63;
    float4 f = *(const float4*)(W + (size_t)(k0 + kr) * N + n0 + nc);
    tile[(nc + 0) * 68 + kr] = f2bf(f.x);
    tile[(nc + 1) * 68 + kr] = f2bf(f.y);
    tile[(nc + 2) * 68 + kr] = f2bf(f.z);
    tile[(nc + 3) * 68 + kr] = f2bf(f.w);
  }
  __syncthreads();
#pragma unroll
  for (int p = 0; p < 4; ++p) {
    int lin = p * 1024 + t * 4;
    int nr = lin >> 6, kc = lin & 63;
    short4_t s = *(const short4_t*)&tile[nr * 68 + kc];
    *(short4_t*)((short*)Wt + (size_t)(noff + n0 + nr) * K + k0 + kc) = s;
  }
}

__global__ __launch_bounds__(256) void ln_kernel(
    const float* __restrict__ x, const float* __restrict__ gamma,
    const float* __restrict__ beta, int gbstride, float addone,
    int rows_per_b, bf16* __restrict__ out) {
  int row = blockIdx.x;
  int t = threadIdx.x;
  const float* xr = x + (size_t)row * DIMX;
  float4 v0 = *(const float4*)(xr + t * 8);
  float4 v1 = *(const float4*)(xr + t * 8 + 4);
  float vv[8] = {v0.x, v0.y, v0.z, v0.w, v1.x, v1.y, v1.z, v1.w};
  float s = 0.f, ss = 0.f;
#pragma unroll
  for (int i = 0; i < 8; ++i) { s += vv[i]; ss += vv[i] * vv[i]; }
  __shared__ float red[8];
  s = wred_sum(s); ss = wred_sum(ss);
  int wid = t >> 6;
  if ((t & 63) == 0) { red[wid] = s; red[4 + wid] = ss; }
  __syncthreads();
  float sum = red[0] + red[1] + red[2] + red[3];
  float sumsq = red[4] + red[5] + red[6] + red[7];
  float mean = sum * (1.f / DIMX);
  float var = sumsq * (1.f / DIMX) - mean * mean;
  float rs = rsqrtf(var + LN_EPS);
  int b = row / rows_per_b;
  const float* g = gamma + (size_t)b * gbstride;
  const float* be = beta + (size_t)b * gbstride;
  short8_t o;
#pragma unroll
  for (int i = 0; i < 8; ++i) {
    int d = t * 8 + i;
    float y = (vv[i] - mean) * rs;
    o[i] = f2bf(y * (addone + g[d]) + be[d]);
  }
  *(short8_t*)((short*)out + (size_t)row * DIMX + t * 8) = o;
}

// RMSNorm+RoPE; blockIdx.y selects (w0,out0) vs (w1,out1), src offset y*DIMX
__global__ __launch_bounds__(256) void rms_rope_kernel(
    const bf16* __restrict__ x, int xstride, const float* __restrict__ w0,
    const float* __restrict__ w1, const float* __restrict__ fcos,
    const float* __restrict__ fsin, int do_rope,
    bf16* __restrict__ out0, bf16* __restrict__ out1) {
  int row = blockIdx.x;
  int t = threadIdx.x;
  int sel = blockIdx.y;
  const float* w = sel ? w1 : w0;
  bf16* out = sel ? out1 : out0;
  short8_t xi = *(const short8_t*)((const short*)x + (size_t)row * xstride + sel * DIMX + t * 8);
  float vv[8];
#pragma unroll
  for (int i = 0; i < 8; ++i) vv[i] = bf2f(xi[i]);
  float ss = 0.f;
#pragma unroll
  for (int i = 0; i < 8; ++i) ss += vv[i] * vv[i];
  __shared__ float red[4];
  ss = wred_sum(ss);
  int wid = t >> 6;
  if ((t & 63) == 0) red[wid] = ss;
  __syncthreads();
  float sumsq = red[0] + red[1] + red[2] + red[3];
  float rs = rsqrtf(sumsq * (1.f / DIMX) + LN_EPS);
  float y[8];
#pragma unroll
  for (int i = 0; i < 8; ++i) y[i] = vv[i] * rs * w[t * 8 + i];
  if (do_rope) {
    int s = row % SLEN;
    int f = s >> 8, hh = (s >> 4) & 15, ww = s & 15;
    int jb = ((t * 8) % HDIM) >> 1;
#pragma unroll
    for (int p = 0; p < 4; ++p) {
      int j = jb + p;
      int src = (j < 22) ? f : ((j < 43) ? hh : ww);
      float c = fcos[src * 64 + j];
      float sn = fsin[src * 64 + j];
      float xr_ = y[2 * p], xim = y[2 * p + 1];
      y[2 * p] = xr_ * c - xim * sn;
      y[2 * p + 1] = xr_ * sn + xim * c;
    }
  }
  short8_t o;
#pragma unroll
  for (int i = 0; i < 8; ++i) o[i] = f2bf(y[i]);
  *(short8_t*)((short*)out + (size_t)row * DIMX + t * 8) = o;
}

// merged cross-attn RMS: rows [0,nq) from xq (stride DIMX) -> outq;
// rows [nq, nq+nk) from xkv (stride 2*DIMX) -> outk.  No RoPE.
__global__ __launch_bounds__(256) void rms_mix_kernel(
    const bf16* __restrict__ xq, const float* __restrict__ wq, bf16* __restrict__ outq,
    const bf16* __restrict__ xkv, const float* __restrict__ wk, bf16* __restrict__ outk,
    int nq) {
  int row = blockIdx.x;
  int t = threadIdx.x;
  const short* src;
  const float* w;
  short* dst;
  if (row < nq) {
    src = (const short*)xq + (size_t)row * DIMX;
    w = wq;
    dst = (short*)outq + (size_t)row * DIMX;
  } else {
    int r = row - nq;
    src = (const short*)xkv + (size_t)r * 2 * DIMX;
    w = wk;
    dst = (short*)outk + (size_t)r * DIMX;
  }
  short8_t xi = *(const short8_t*)(src + t * 8);
  float vv[8];
#pragma unroll
  for (int i = 0; i < 8; ++i) vv[i] = bf2f(xi[i]);
  float ss = 0.f;
#pragma unroll
  for (int i = 0; i < 8; ++i) ss += vv[i] * vv[i];
  __shared__ float red[4];
  ss = wred_sum(ss);
  int wid = t >> 6;
  if ((t & 63) == 0) red[wid] = ss;
  __syncthreads();
  float sumsq = red[0] + red[1] + red[2] + red[3];
  float rs = rsqrtf(sumsq * (1.f / DIMX) + LN_EPS);
  short8_t o;
#pragma unroll
  for (int i = 0; i < 8; ++i) o[i] = f2bf(vv[i] * rs * w[t * 8 + i]);
  *(short8_t*)(dst + t * 8) = o;
}

// ------------- 256x256 8-phase GEMM v3.1 (R11-proven, 16x16x32) -----
#define RDAe(dst, bufL, mh) { _Pragma("unroll") for (int mi = 0; mi < 4; ++mi) { \
    dst[mi][0] = *(const short8_t*)&AsF[aA[mi][0] + (mh) * 4096 + (bufL) * 16384]; \
    dst[mi][1] = *(const short8_t*)&AsF[aA[mi][1] + (mh) * 4096 + (bufL) * 16384]; } }
#define RDBe(dst, bufL, nh) { _Pragma("unroll") for (int nj = 0; nj < 2; ++nj) { \
    dst[nj][0] = *(const short8_t*)&BsF[aB[nj][0] + (nh) * 2048 + (bufL) * 16384]; \
    dst[nj][1] = *(const short8_t*)&BsF[aB[nj][1] + (nh) * 2048 + (bufL) * 16384]; } }
#define MMAQ(aS, bS, mh, nh) { _Pragma("unroll") for (int kq = 0; kq < 2; ++kq) \
    _Pragma("unroll") for (int mi = 0; mi < 4; ++mi) \
    _Pragma("unroll") for (int nj = 0; nj < 2; ++nj) \
      acc[(mh)*4+mi][(nh)*2+nj] = __builtin_amdgcn_mfma_f32_16x16x32_bf16( \
          aS[mi][kq], bS[nj][kq], acc[(mh)*4+mi][(nh)*2+nj], 0, 0, 0); }
#define STA(bufL, kkE, late) { _Pragma("unroll") for (int i = 0; i < 2; ++i) \
    gload16(Ap + gA[i][late] + (kkE), &AsF[ldsA[i][late] + (bufL) * 16384]); }
#define STB(bufL, kkE, late) { _Pragma("unroll") for (int i = 0; i < 2; ++i) \
    gload16(Bp + gB[i][late] + (kkE), &BsF[ldsB[i][late] + (bufL) * 16384]); }
#define BAR asm volatile("s_barrier" ::: "memory")
#define VMCNT(n) asm volatile("s_waitcnt vmcnt(" #n ")" ::: "memory")
#define SETPRIO(x) __builtin_amdgcn_s_setprio(x)

__global__ __launch_bounds__(512) void gemm256(
    const bf16* __restrict__ A, const bf16* __restrict__ Bt,
    const float* __restrict__ bias,
    float* outF, bf16* outB,
    const float* resid, const float* __restrict__ scale,
    int scstride, int rows_per_b, int gn, int N, int K,
    int klen, int nsplit, long long spoff, int mode) {
  __shared__ short AsF[2 * 16384];
  __shared__ short BsF[2 * 16384];
  int t = threadIdx.x, lane = t & 63, wv = t >> 6;
  int l15 = lane & 15, koff = lane >> 4;
  int wm = wv >> 2, wn = wv & 3;
  int nwgx = gridDim.x, ksp = 0, bid = blockIdx.x;
  if (nsplit == 2) { nwgx >>= 1; if (bid >= nwgx) { ksp = 1; bid -= nwgx; } }
  int cpx = nwgx >> 3;
  int swz = (bid & 7) * cpx + (bid >> 3);
  int by = swz / gn, bx = swz % gn;
  int m0 = by << 8, n0 = bx << 8;
  int kbeg = ksp * klen;

  f32x4 acc[8][4] = {};
  short8_t ae[4][2], al[4][2], be[2][2], bl[2][2];

  int aA[4][2], aB[2][2];
#pragma unroll
  for (int mi = 0; mi < 4; ++mi) {
    int r = wm * 128 + mi * 16 + l15;
#pragma unroll
    for (int kq = 0; kq < 2; ++kq)
      aA[mi][kq] = r * 64 + (((kq * 4 + koff) ^ (r & 7)) << 3);
  }
#pragma unroll
  for (int nj = 0; nj < 2; ++nj) {
    int r = wn * 64 + nj * 16 + l15;
#pragma unroll
    for (int kq = 0; kq < 2; ++kq)
      aB[nj][kq] = r * 64 + (((kq * 4 + koff) ^ (r & 7)) << 3);
  }

  int srcChunk = ((lane & 7) ^ (lane >> 3)) << 3;
  int rowInSlot = lane >> 3;
  const short* Ap = (const short*)A;
  const short* Bp = (const short*)Bt;
  size_t gA[2][2], gB[2][2];
  int ldsA[2][2], ldsB[2][2];
#pragma unroll
  for (int i = 0; i < 2; ++i) {
    int idx = i * 8 + wv;
#pragma unroll
    for (int late = 0; late < 2; ++late) {
      int slotA = ((idx >> 3) << 4) + (idx & 7) + late * 8;
      gA[i][late] = (size_t)(m0 + slotA * 8 + rowInSlot) * K + srcChunk;
      ldsA[i][late] = slotA << 9;
      int slotB = ((idx >> 2) << 3) + (idx & 3) + late * 4;
      gB[i][late] = (size_t)(n0 + slotB * 8 + rowInSlot) * K + srcChunk;
      ldsB[i][late] = slotB << 9;
    }
  }

  int NT = klen >> 6;
  STA(0, kbeg, 0); STB(0, kbeg, 0); STA(0, kbeg, 1); STB(0, kbeg, 1);
  STA(1, kbeg + 64, 0); STB(1, kbeg + 64, 0);
  VMCNT(4); BAR;

  for (int tt = 0; tt < NT; tt += 2) {
    int k1 = kbeg + (((tt + 1) < NT ? (tt + 1) : 0) << 6);
    int k2 = kbeg + (((tt + 2) < NT ? (tt + 2) : 0) << 6);
    int k3 = kbeg + (((tt + 3) < NT ? (tt + 3) : 0) << 6);
    RDAe(ae, 0, 0); RDBe(be, 0, 0);
    STA(1, k1, 1);
    BAR; SETPRIO(1); MMAQ(ae, be, 0, 0); SETPRIO(0); RDBe(bl, 0, 1); BAR;
    STB(1, k1, 1);
    BAR; SETPRIO(1); MMAQ(ae, bl, 0, 1); SETPRIO(0); RDAe(al, 0, 1); BAR;
    STA(0, k2, 0);
    BAR; SETPRIO(1); MMAQ(al, bl, 1, 1); SETPRIO(0); BAR;
    STB(0, k2, 0);
    BAR; SETPRIO(1); MMAQ(al, be, 1, 0); SETPRIO(0); VMCNT(4); BAR;
    RDAe(ae, 1, 0); RDBe(be, 1, 0);
    STA(0, k2, 1);
    BAR; SETPRIO(1); MMAQ(ae, be, 0, 0); SETPRIO(0); RDBe(bl, 1, 1); BAR;
    STB(0, k2, 1);
    BAR; SETPRIO(1); MMAQ(ae, bl, 0, 1); SETPRIO(0); RDAe(al, 1, 1); BAR;
    STA(1, k3, 0);
    BAR; SETPRIO(1); MMAQ(al, bl, 1, 1); SETPRIO(0); BAR;
    STB(1, k3, 0);
    BAR; SETPRIO(1); MMAQ(al, be, 1, 0); SETPRIO(0); VMCNT(4); BAR;
  }
  VMCNT(0);

  int mo = m0 + wm * 128, no = n0 + wn * 64;
  long long so = (long long)ksp * spoff;
#pragma unroll
  for (int mf = 0; mf < 8; ++mf)
#pragma unroll
    for (int nf = 0; nf < 4; ++nf) {
      int n = no + nf * 16 + l15;
      float bia = (mode == 5) ? 0.f : bias[n];
#pragma unroll
      for (int r = 0; r < 4; ++r) {
        int m = mo + mf * 16 + koff * 4 + r;
        float vv = acc[mf][nf][r] + bia;
        size_t idx = (size_t)m * N + n;
        if (mode == 1) {
          ((short*)outB)[idx] = f2bf(vv);
        } else if (mode == 2) {
          float u = 0.7978845608f * (vv + 0.044715f * vv * vv * vv);
          float g = vv / (1.f + exp2f(-2.88539009f * u));
          ((short*)outB)[idx] = f2bf(g);
        } else if (mode == 5) {
          ((short*)outB)[idx + so] = f2bf(vv);
        } else {
          float sc = scale ? scale[(size_t)(m / rows_per_b) * scstride + n] : 1.0f;
          outF[idx] = resid[idx] + vv * sc;
        }
      }
    }
}

// ---------------- 128x128 2-phase GEMM (proven R3) --------
__global__ __launch_bounds__(256) void gemm_bt(
    const bf16* __restrict__ A, const bf16* __restrict__ Bt,
    const float* __restrict__ bias,
    float* outF, bf16* outB,
    const float* resid, const float* __restrict__ scale,
    int scstride, int rows_per_b, int gn, int N, int K, int mode) {
  __shared__ short As[2][128 * 64];
  __shared__ short Bs[2][128 * 64];
  int t = threadIdx.x, lane = t & 63, wv = t >> 6;
  int nwg = gridDim.x, cpx = nwg >> 3;
  int swz = (blockIdx.x & 7) * cpx + (blockIdx.x >> 3);
  int by = swz / gn, bx = swz % gn;
  int m0 = by << 7, n0 = bx << 7;
  f32x4 acc[4][4] = {};
  int mo_l = (wv >> 1) << 6, no_l = (wv & 1) << 6;

  int srow[4], scol[4];
#pragma unroll
  for (int j = 0; j < 4; ++j) {
    srow[j] = wv * 32 + j * 8 + (lane >> 3);
    scol[j] = ((lane & 7) ^ (srow[j] & 7)) << 3;
  }
  const short* Ap = (const short*)A;
  const short* Bp = (const short*)Bt;

  int koff = lane >> 4;
  int rowA[4], rowB[4];
#pragma unroll
  for (int i = 0; i < 4; ++i) {
    rowA[i] = mo_l + i * 16 + (lane & 15);
    rowB[i] = no_l + i * 16 + (lane & 15);
  }

  auto stage = [&](int bufI, int kk) {
#pragma unroll
    for (int j = 0; j < 4; ++j) {
      gload16(Ap + (size_t)(m0 + srow[j]) * K + kk + scol[j],
              &As[bufI][(wv * 32 + j * 8) * 64]);
      gload16(Bp + (size_t)(n0 + srow[j]) * K + kk + scol[j],
              &Bs[bufI][(wv * 32 + j * 8) * 64]);
    }
  };

  stage(0, 0);
  __syncthreads();
  int cur = 0;
  for (int kk = 0; kk < K; kk += 64) {
    int nxt = cur ^ 1;
    if (kk + 64 < K) stage(nxt, kk + 64);
    short8_t af[2][4], bfv[2][4];
#pragma unroll
    for (int h = 0; h < 2; ++h)
#pragma unroll
      for (int i = 0; i < 4; ++i) {
        int cA = ((h * 4 + koff) ^ (rowA[i] & 7)) << 3;
        af[h][i] = *(const short8_t*)&As[cur][rowA[i] * 64 + cA];
        int cB = ((h * 4 + koff) ^ (rowB[i] & 7)) << 3;
        bfv[h][i] = *(const short8_t*)&Bs[cur][rowB[i] * 64 + cB];
      }
#pragma unroll
    for (int h = 0; h < 2; ++h)
#pragma unroll
      for (int mt = 0; mt < 4; ++mt)
#pragma unroll
        for (int nt = 0; nt < 4; ++nt)
          acc[mt][nt] = __builtin_amdgcn_mfma_f32_16x16x32_bf16(af[h][mt], bfv[h][nt], acc[mt][nt], 0, 0, 0);
    __syncthreads();
    cur = nxt;
  }

  int mo = m0 + mo_l, no = n0 + no_l;
#pragma unroll
  for (int mt = 0; mt < 4; ++mt)
#pragma unroll
    for (int nt = 0; nt < 4; ++nt) {
      int n = no + nt * 16 + (lane & 15);
      float bia = bias[n];
#pragma unroll
      for (int r = 0; r < 4; ++r) {
        int m = mo + mt * 16 + (lane >> 4) * 4 + r;
        float vv = acc[mt][nt][r] + bia;
        size_t idx = (size_t)m * N + n;
        if (mode == 1) {
          ((short*)outB)[idx] = f2bf(vv);
        } else if (mode == 2) {
          float g = 0.5f * vv * (1.f + tanhf(0.7978845608f * (vv + 0.044715f * vv * vv * vv)));
          ((short*)outB)[idx] = f2bf(g);
        } else {
          float sc = scale ? scale[(size_t)(m / rows_per_b) * scstride + n] : 1.0f;
          outF[idx] = resid[idx] + vv * sc;
        }
      }
    }
}

// Flash attention v5 (R13-proven): XCD swizzle, T14 async stage, defer-max,
// swizzled V^T, packed-dword P, log2 softmax, setprio.
__global__ __launch_bounds__(512) void attn_kernel(
    const bf16* __restrict__ q, const bf16* __restrict__ k,
    const bf16* __restrict__ v, bf16* __restrict__ y,
    int QL, int KVL, int qs, int ks, int vs, float scl) {
  __shared__ short Kt[64 * 136];
  __shared__ short Vt[128 * 72];
  __shared__ unsigned Pl[128 * 36];
  __shared__ float rl[8 * 16];
  __shared__ float ll[8 * 16];
  int t = threadIdx.x, lane = t & 63, wv = t >> 6;
  int l15 = lane & 15, koff = lane >> 4;
  int id = blockIdx.x;
  int c = id & 7, j = id >> 3;
  int bh = c * 4 + (j >> 4);
  int qx = j & 15;
  int b = bh / NHEADS, h = bh % NHEADS;
  int q0 = qx * 128 + wv * 16;
  const short* qp = (const short*)q;
  const short* kp = (const short*)k;
  const short* vp = (const short*)v;
  const float c1 = scl * 1.44269504088896f;
  short8_t qf[4];
  {
    size_t qbase = ((size_t)(b * QL) + q0 + l15) * qs + h * HDIM + koff * 8;
#pragma unroll
    for (int kc = 0; kc < 4; ++kc) qf[kc] = *(const short8_t*)(qp + qbase + kc * 32);
  }
  f32x4 o[8] = {};
  float m_run = -1e30f, l_run = 0.f;
  int strow = t >> 3, stcol = (t & 7) * 16;
  size_t kbase = (size_t)(b * KVL + strow) * ks + h * HDIM + stcol;
  size_t vbase = (size_t)(b * KVL + strow) * vs + h * HDIM + stcol;
  short8_t kreg[2], vreg[2];
  kreg[0] = *(const short8_t*)(kp + kbase);
  kreg[1] = *(const short8_t*)(kp + kbase + 8);
  vreg[0] = *(const short8_t*)(vp + vbase);
  vreg[1] = *(const short8_t*)(vp + vbase + 8);
  for (int kt0 = 0; kt0 < KVL; kt0 += 64) {
#pragma unroll
    for (int cc = 0; cc < 2; ++cc)
      *(short8_t*)&Kt[strow * 136 + stcol + cc * 8] = kreg[cc];
#pragma unroll
    for (int cc = 0; cc < 2; ++cc) {
#pragma unroll
      for (int e = 0; e < 8; ++e) {
        int d = stcol + cc * 8 + e;
        Vt[d * 72 + (strow ^ ((d >> 2) & 0x38))] = vreg[cc][e];
      }
    }
    if (kt0 + 64 < KVL) {
      size_t kb2 = kbase + (size_t)(kt0 + 64) * ks;
      size_t vb2 = vbase + (size_t)(kt0 + 64) * vs;
      kreg[0] = *(const short8_t*)(kp + kb2);
      kreg[1] = *(const short8_t*)(kp + kb2 + 8);
      vreg[0] = *(const short8_t*)(vp + vb2);
      vreg[1] = *(const short8_t*)(vp + vb2 + 8);
    }
    __syncthreads();
    f32x4 st[4];
    SETPRIO(1);
#pragma unroll
    for (int kt = 0; kt < 4; ++kt) {
      f32x4 aa = {0.f, 0.f, 0.f, 0.f};
#pragma unroll
      for (int kc = 0; kc < 4; ++kc) {
        short8_t kf = *(const short8_t*)&Kt[(kt * 16 + l15) * 136 + kc * 32 + koff * 8];
        aa = __builtin_amdgcn_mfma_f32_16x16x32_bf16(kf, qf[kc], aa, 0, 0, 0);
      }
      st[kt] = aa;
    }
    SETPRIO(0);
    float mk[4];
#pragma unroll
    for (int kt = 0; kt < 4; ++kt)
      mk[kt] = fmaxf(fmaxf(st[kt][0], st[kt][1]), fmaxf(st[kt][2], st[kt][3]));
    float mt_ = fmaxf(fmaxf(mk[0], mk[1]), fmaxf(mk[2], mk[3]));
    mt_ = fmaxf(mt_, __shfl_xor(mt_, 16, 64));
    mt_ = fmaxf(mt_, __shfl_xor(mt_, 32, 64));
    float mtc = mt_ * c1;
    bool nos = __all(mtc <= m_run + 8.0f);
    float m_new = nos ? m_run : fmaxf(m_run, mtc);
    float pk[4];
#pragma unroll
    for (int kt = 0; kt < 4; ++kt) {
#pragma unroll
      for (int r = 0; r < 4; ++r)
        st[kt][r] = exp2f(fmaf(st[kt][r], c1, -m_new));
      pk[kt] = (st[kt][0] + st[kt][1]) + (st[kt][2] + st[kt][3]);
    }
    float ps = (pk[0] + pk[1]) + (pk[2] + pk[3]);
    ps += __shfl_xor(ps, 16, 64);
    ps += __shfl_xor(ps, 32, 64);
    if (!nos) {
      float rfac = exp2f(m_run - m_new);
      l_run = l_run * rfac + ps;
      m_run = m_new;
      if (lane < 16) rl[wv * 16 + lane] = rfac;
      float rr[4];
#pragma unroll
      for (int r = 0; r < 4; ++r) rr[r] = rl[wv * 16 + koff * 4 + r];
#pragma unroll
      for (int dt = 0; dt < 8; ++dt)
#pragma unroll
        for (int r = 0; r < 4; ++r) o[dt][r] *= rr[r];
    } else {
      l_run += ps;
    }
#pragma unroll
    for (int kt = 0; kt < 4; ++kt)
#pragma unroll
      for (int rp = 0; rp < 2; ++rp) {
        unsigned lo = (unsigned short)f2bf(st[kt][2 * rp]);
        unsigned hi = (unsigned short)f2bf(st[kt][2 * rp + 1]);
        Pl[(wv * 16 + l15) * 36 + kt * 8 + koff * 2 + rp] = lo | (hi << 16);
      }
    SETPRIO(1);
#pragma unroll
    for (int kc2 = 0; kc2 < 2; ++kc2) {
      short8_t pa = *(const short8_t*)&Pl[(wv * 16 + l15) * 36 + kc2 * 16 + koff * 4];
#pragma unroll
      for (int dt = 0; dt < 8; ++dt) {
        int drow = dt * 16 + l15;
        int kv0 = (kc2 * 32 + koff * 8) ^ ((drow >> 2) & 0x38);
        short8_t vf = *(const short8_t*)&Vt[drow * 72 + kv0];
        o[dt] = __builtin_amdgcn_mfma_f32_16x16x32_bf16(pa, vf, o[dt], 0, 0, 0);
      }
    }
    SETPRIO(0);
    __syncthreads();
  }
  if (lane < 16) ll[wv * 16 + lane] = 1.f / l_run;
  float li[4];
#pragma unroll
  for (int r = 0; r < 4; ++r) li[r] = ll[wv * 16 + koff * 4 + r];
  short* yp = (short*)y;
#pragma unroll
  for (int dt = 0; dt < 8; ++dt)
#pragma unroll
    for (int r = 0; r < 4; ++r) {
      int qq = q0 + koff * 4 + r;
      int d = dt * 16 + l15;
      yp[((size_t)(b * QL) + qq) * DIMX + h * HDIM + d] = f2bf(o[dt][r] * li[r]);
    }
}

// ws layout (bytes)
#define OFF_EM    0ull
#define OFF_BQKV  (512ull << 10)
#define OFF_BCKV  (560ull << 10)
#define OFF_XN    (1ull << 20)
#define OFF_QKV   (17ull << 20)   // fused qkv: 48 MB (17..65)
#define OFF_CAQ   (17ull << 20)
#define OFF_KV    (33ull << 20)
#define OFF_QB    (65ull << 20)
#define OFF_KB    (81ull << 20)
#define OFF_YB    (97ull << 20)
#define OFF_CTX   (113ull << 20)
#define OFF_WBUF  (117ull << 20)
#define OFF_HB    (17ull << 20)   // FFN hidden 64 MB (17..81)
#define OFF_PS    (81ull << 20)   // FFN2 partials 2x16 MB (81..113) - no hb overlap

extern "C" void kernel_launch(void* const* d_in, const int* in_sizes, int n_in,
                              void* d_out, int out_size, void* d_ws, size_t ws_size,
                              hipStream_t stream) {
  const float* x       = (const float*)d_in[0];
  const float* e       = (const float*)d_in[1];
  const float* context = (const float*)d_in[2];
  const float* fcos    = (const float*)d_in[3];
  const float* fsin    = (const float*)d_in[4];
  const float* modu    = (const float*)d_in[5];
  const float* sa_wq = (const float*)d_in[6];  const float* sa_bq = (const float*)d_in[7];
  const float* sa_wk = (const float*)d_in[8];  const float* sa_bk = (const float*)d_in[9];
  const float* sa_wv = (const float*)d_in[10]; const float* sa_bv = (const float*)d_in[11];
  const float* sa_wo = (const float*)d_in[12]; const float* sa_bo = (const float*)d_in[13];
  const float* sa_nq = (const float*)d_in[14]; const float* sa_nk = (const float*)d_in[15];
  const float* ca_wq = (const float*)d_in[16]; const float* ca_bq = (const float*)d_in[17];
  const float* ca_wk = (const float*)d_in[18]; const float* ca_bk = (const float*)d_in[19];
  const float* ca_wv = (const float*)d_in[20]; const float* ca_bv = (const float*)d_in[21];
  const float* ca_wo = (const float*)d_in[22]; const float* ca_bo = (const float*)d_in[23];
  const float* ca_nq = (const float*)d_in[24]; const float* ca_nk = (const float*)d_in[25];
  const float* n3_w  = (const float*)d_in[26]; const float* n3_b  = (const float*)d_in[27];
  const float* f_w1  = (const float*)d_in[28]; const float* f_b1  = (const float*)d_in[29];
  const float* f_w2  = (const float*)d_in[30]; const float* f_b2  = (const float*)d_in[31];

  char* ws = (char*)d_ws;
  float* em   = (float*)(ws + OFF_EM);
  float* bqkv = (float*)(ws + OFF_BQKV);
  float* bckv = (float*)(ws + OFF_BCKV);
  bf16* xn    = (bf16*)(ws + OFF_XN);
  bf16* qkvb  = (bf16*)(ws + OFF_QKV);
  bf16* caqb  = (bf16*)(ws + OFF_CAQ);
  bf16* kvb   = (bf16*)(ws + OFF_KV);
  bf16* qb    = (bf16*)(ws + OFF_QB);
  bf16* kb    = (bf16*)(ws + OFF_KB);
  bf16* yb    = (bf16*)(ws + OFF_YB);
  bf16* ctxb  = (bf16*)(ws + OFF_CTX);
  bf16* wbuf  = (bf16*)(ws + OFF_WBUF);
  bf16* hb    = (bf16*)(ws + OFF_HB);
  bf16* ps    = (bf16*)(ws + OFF_PS);
  float* xw   = (float*)d_out;

  const int M = BSZ * SLEN;
  const int MC = BSZ * CTXL;
  const float scl = 0.08838834764831845f;
  const size_t WSTRIDE = (size_t)DIMX * DIMX;

#define GEMM256(Am, Bt, Md, Nd, Kd, bias, oF, oB, res, sc, scs, rpb, mode) \
  gemm256<<<((Md) / 256) * ((Nd) / 256), 512, 0, stream>>>(Am, Bt, bias, oF, oB, res, sc, \
                                                           scs, rpb, (Nd) / 256, Nd, Kd, Kd, 1, 0ll, mode)
#define GEMM128(Am, Bt, Md, Nd, Kd, bias, oF, oB, res, sc, scs, rpb, mode) \
  gemm_bt<<<((Md) / 128) * ((Nd) / 128), 256, 0, stream>>>(Am, Bt, bias, oF, oB, res, sc, scs, rpb, (Nd) / 128, Nd, Kd, mode)

  prep_kernel<<<(BSZ * 6 * DIMX + 5 * DIMX + MC * DIMX / 8 + 255) / 256, 256, 0, stream>>>(
      e, modu, em, sa_bq, sa_bk, sa_bv, bqkv, ca_bk, ca_bv, bckv, context, ctxb);

  // --- self attention ---
  ln_kernel<<<M, 256, 0, stream>>>(x, em + 1 * DIMX, em + 0 * DIMX, 6 * DIMX, 1.0f, SLEN, xn);

  transpose_w4<<<dim3(DIMX / 64, DIMX / 64, 4), 256, 0, stream>>>(
      sa_wq, sa_wk, sa_wv, sa_wo, wbuf, DIMX, DIMX);

  // fused QKV: N=6144, grid 384
  GEMM256(xn, wbuf, M, 3 * DIMX, DIMX, bqkv, nullptr, qkvb, nullptr, nullptr, 0, 1, 1);

  rms_rope_kernel<<<dim3(M, 2), 256, 0, stream>>>(qkvb, 3 * DIMX, sa_nq, sa_nk,
                                                  fcos, fsin, 1, qb, kb);

  attn_kernel<<<512, 512, 0, stream>>>(qb, kb, (bf16*)((short*)qkvb + 2 * DIMX), yb,
                                       SLEN, SLEN, DIMX, DIMX, 3 * DIMX, scl);

  GEMM128(yb, wbuf + 3 * WSTRIDE, M, DIMX, DIMX, sa_bo, xw, nullptr,
          x, em + 2 * DIMX, 6 * DIMX, SLEN, 3);

  // --- cross attention ---
  ln_kernel<<<M, 256, 0, stream>>>(xw, n3_w, n3_b, 0, 0.0f, SLEN, xn);

  transpose_w4<<<dim3(DIMX / 64, DIMX / 64, 4), 256, 0, stream>>>(
      ca_wq, ca_wk, ca_wv, ca_wo, wbuf, DIMX, DIMX);

  GEMM128(xn, wbuf, M, DIMX, DIMX, ca_bq, nullptr, caqb, nullptr, nullptr, 0, 1, 1);
  GEMM128(ctxb, wbuf + WSTRIDE, MC, 2 * DIMX, DIMX, bckv, nullptr, kvb,
          nullptr, nullptr, 0, 1, 1);

  rms_mix_kernel<<<M + MC, 256, 0, stream>>>(caqb, ca_nq, qb, kvb, ca_nk, kb, M);

  attn_kernel<<<512, 512, 0, stream>>>(qb, kb, (bf16*)((short*)kvb + DIMX), yb,
                                       SLEN, CTXL, DIMX, DIMX, 2 * DIMX, scl);

  GEMM128(yb, wbuf + 3 * WSTRIDE, M, DIMX, DIMX, ca_bo, xw, nullptr,
          xw, nullptr, 0, SLEN, 3);

  // --- FFN ---
  ln_kernel<<<M, 256, 0, stream>>>(xw, em + 4 * DIMX, em + 3 * DIMX, 6 * DIMX, 1.0f, SLEN, xn);

  transpose_w4<<<dim3(FFND / 64, DIMX / 64, 1), 256, 0, stream>>>(
      f_w1, nullptr, nullptr, nullptr, wbuf, DIMX, FFND);
  GEMM256(xn, wbuf, M, FFND, DIMX, f_b1, nullptr, hb, nullptr, nullptr, 0, 1, 2);

  transpose_w4<<<dim3(DIMX / 64, FFND / 64, 1), 256, 0, stream>>>(
      f_w2, nullptr, nullptr, nullptr, wbuf, FFND, DIMX);
  gemm256<<<2 * (M / 256) * (DIMX / 256), 512, 0, stream>>>(
      hb, wbuf, f_b2, nullptr, ps, nullptr, nullptr, 0, 1, DIMX / 256, DIMX,
      FFND, FFND / 2, 2, (long long)M * DIMX, 5);
  combine_kernel<<<M * DIMX / 8 / 256, 256, 0, stream>>>(
      ps, ps + (size_t)M * DIMX, f_b2, xw, em + 5 * DIMX, 6 * DIMX, SLEN, xw, DIMX);
}

// Round 15
// 962.399 us; speedup vs baseline: 1.0281x; 1.0281x over previous
//
#include <hip/hip_runtime.h>
#include <hip/hip_bf16.h>
#include <math.h>

#define DIMX 2048
#define SLEN 2048
#define BSZ 2
#define NHEADS 16
#define HDIM 128
#define FFND 8192
#define CTXL 512
#define LN_EPS 1e-6f

typedef __attribute__((ext_vector_type(8))) short short8_t;
typedef __attribute__((ext_vector_type(4))) short short4_t;
typedef __attribute__((ext_vector_type(4))) float f32x4;
typedef __hip_bfloat16 bf16;

__device__ __forceinline__ short f2bf(float f) {
  union { float f; unsigned u; } v; v.f = f;
  return (short)((v.u + 0x7FFFu + ((v.u >> 16) & 1u)) >> 16);
}
__device__ __forceinline__ float bf2f(short s) {
  union { unsigned u; float f; } v; v.u = ((unsigned)(unsigned short)s) << 16;
  return v.f;
}

__device__ __forceinline__ void gload16(const void* g, void* l) {
  __builtin_amdgcn_global_load_lds(
      (const __attribute__((address_space(1))) unsigned int*)g,
      (__attribute__((address_space(3))) unsigned int*)l, 16, 0, 0);
}

__device__ __forceinline__ float wred_sum(float v) {
#pragma unroll
  for (int o = 32; o > 0; o >>= 1) v += __shfl_xor(v, o, 64);
  return v;
}

// fused: em add + bias packs (qkv 3-wide; ckv 2-wide) + context fp32->bf16
__global__ void prep_kernel(const float* __restrict__ e, const float* __restrict__ mod,
                            float* __restrict__ em,
                            const float* __restrict__ sa_bq, const float* __restrict__ sa_bk,
                            const float* __restrict__ sa_bv, float* __restrict__ bqkv,
                            const float* __restrict__ ca_bk, const float* __restrict__ ca_bv,
                            float* __restrict__ bckv,
                            const float* __restrict__ ctx, bf16* __restrict__ ctxb) {
  int i = blockIdx.x * 256 + threadIdx.x;
  if (i < BSZ * 6 * DIMX) { em[i] = e[i] + mod[i % (6 * DIMX)]; return; }
  i -= BSZ * 6 * DIMX;
  if (i < 3 * DIMX) {
    bqkv[i] = (i < DIMX) ? sa_bq[i] : (i < 2 * DIMX) ? sa_bk[i - DIMX] : sa_bv[i - 2 * DIMX];
    return;
  }
  i -= 3 * DIMX;
  if (i < 2 * DIMX) { bckv[i] = (i < DIMX) ? ca_bk[i] : ca_bv[i - DIMX]; return; }
  i -= 2 * DIMX;
  if (i < BSZ * CTXL * DIMX / 8) {
    float4 a = *(const float4*)(ctx + (size_t)i * 8);
    float4 b = *(const float4*)(ctx + (size_t)i * 8 + 4);
    float fv[8] = {a.x, a.y, a.z, a.w, b.x, b.y, b.z, b.w};
    short8_t o;
#pragma unroll
    for (int j = 0; j < 8; ++j) o[j] = f2bf(fv[j]);
    *(short8_t*)((short*)ctxb + (size_t)i * 8) = o;
  }
}

// out = resid + (p0 + p1 + bias) * scale   (FFN2 split-K combine)
__global__ __launch_bounds__(256) void combine_kernel(
    const bf16* __restrict__ p0, const bf16* __restrict__ p1,
    const float* __restrict__ bias, const float* __restrict__ resid,
    const float* __restrict__ scale, int scstride, int rows_per_b,
    float* __restrict__ out, int N) {
  int i8 = blockIdx.x * 256 + threadIdx.x;
  size_t base = (size_t)i8 * 8;
  int n = (int)(base % N);
  int m = (int)(base / N);
  int b = m / rows_per_b;
  short8_t a = *(const short8_t*)((const short*)p0 + base);
  short8_t c = *(const short8_t*)((const short*)p1 + base);
  const float* bi = bias + n;
  const float* sc = scale + (size_t)b * scstride + n;
  const float* rs = resid + base;
  float* o = out + base;
#pragma unroll
  for (int j = 0; j < 8; ++j)
    o[j] = rs[j] + (bf2f(a[j]) + bf2f(c[j]) + bi[j]) * sc[j];
}

// batched: up to 4 weights [K][N] -> Wt bf16 rows [z*N + n][K]
__global__ __launch_bounds__(256) void transpose_w4(
    const float* s0, const float* s1, const float* s2, const float* s3,
    bf16* __restrict__ Wt, int K, int N) {
  __shared__ short tile[64 * 68];
  const float* W = (blockIdx.z == 0) ? s0 : (blockIdx.z == 1) ? s1
                   : (blockIdx.z == 2) ? s2 : s3;
  int noff = blockIdx.z * N;
  int k0 = blockIdx.y << 6, n0 = blockIdx.x << 6;
  int t = threadIdx.x;
#pragma unroll
  for (int p = 0; p < 4; ++p) {
    int lin = p * 1024 + t * 4;
    int kr = lin >> 6, nc = lin & 63;
    float4 f = *(const float4*)(W + (size_t)(k0 + kr) * N + n0 + nc);
    tile[(nc + 0) * 68 + kr] = f2bf(f.x);
    tile[(nc + 1) * 68 + kr] = f2bf(f.y);
    tile[(nc + 2) * 68 + kr] = f2bf(f.z);
    tile[(nc + 3) * 68 + kr] = f2bf(f.w);
  }
  __syncthreads();
#pragma unroll
  for (int p = 0; p < 4; ++p) {
    int lin = p * 1024 + t * 4;
    int nr = lin >> 6, kc = lin & 63;
    short4_t s = *(const short4_t*)&tile[nr * 68 + kc];
    *(short4_t*)((short*)Wt + (size_t)(noff + n0 + nr) * K + k0 + kc) = s;
  }
}

__global__ __launch_bounds__(256) void ln_kernel(
    const float* __restrict__ x, const float* __restrict__ gamma,
    const float* __restrict__ beta, int gbstride, float addone,
    int rows_per_b, bf16* __restrict__ out) {
  int row = blockIdx.x;
  int t = threadIdx.x;
  const float* xr = x + (size_t)row * DIMX;
  float4 v0 = *(const float4*)(xr + t * 8);
  float4 v1 = *(const float4*)(xr + t * 8 + 4);
  float vv[8] = {v0.x, v0.y, v0.z, v0.w, v1.x, v1.y, v1.z, v1.w};
  float s = 0.f, ss = 0.f;
#pragma unroll
  for (int i = 0; i < 8; ++i) { s += vv[i]; ss += vv[i] * vv[i]; }
  __shared__ float red[8];
  s = wred_sum(s); ss = wred_sum(ss);
  int wid = t >> 6;
  if ((t & 63) == 0) { red[wid] = s; red[4 + wid] = ss; }
  __syncthreads();
  float sum = red[0] + red[1] + red[2] + red[3];
  float sumsq = red[4] + red[5] + red[6] + red[7];
  float mean = sum * (1.f / DIMX);
  float var = sumsq * (1.f / DIMX) - mean * mean;
  float rs = rsqrtf(var + LN_EPS);
  int b = row / rows_per_b;
  const float* g = gamma + (size_t)b * gbstride;
  const float* be = beta + (size_t)b * gbstride;
  short8_t o;
#pragma unroll
  for (int i = 0; i < 8; ++i) {
    int d = t * 8 + i;
    float y = (vv[i] - mean) * rs;
    o[i] = f2bf(y * (addone + g[d]) + be[d]);
  }
  *(short8_t*)((short*)out + (size_t)row * DIMX + t * 8) = o;
}

// RMSNorm+RoPE; blockIdx.y selects (w0,out0) vs (w1,out1), src offset y*DIMX
__global__ __launch_bounds__(256) void rms_rope_kernel(
    const bf16* __restrict__ x, int xstride, const float* __restrict__ w0,
    const float* __restrict__ w1, const float* __restrict__ fcos,
    const float* __restrict__ fsin, int do_rope,
    bf16* __restrict__ out0, bf16* __restrict__ out1) {
  int row = blockIdx.x;
  int t = threadIdx.x;
  int sel = blockIdx.y;
  const float* w = sel ? w1 : w0;
  bf16* out = sel ? out1 : out0;
  short8_t xi = *(const short8_t*)((const short*)x + (size_t)row * xstride + sel * DIMX + t * 8);
  float vv[8];
#pragma unroll
  for (int i = 0; i < 8; ++i) vv[i] = bf2f(xi[i]);
  float ss = 0.f;
#pragma unroll
  for (int i = 0; i < 8; ++i) ss += vv[i] * vv[i];
  __shared__ float red[4];
  ss = wred_sum(ss);
  int wid = t >> 6;
  if ((t & 63) == 0) red[wid] = ss;
  __syncthreads();
  float sumsq = red[0] + red[1] + red[2] + red[3];
  float rs = rsqrtf(sumsq * (1.f / DIMX) + LN_EPS);
  float y[8];
#pragma unroll
  for (int i = 0; i < 8; ++i) y[i] = vv[i] * rs * w[t * 8 + i];
  if (do_rope) {
    int s = row % SLEN;
    int f = s >> 8, hh = (s >> 4) & 15, ww = s & 15;
    int jb = ((t * 8) % HDIM) >> 1;
#pragma unroll
    for (int p = 0; p < 4; ++p) {
      int j = jb + p;
      int src = (j < 22) ? f : ((j < 43) ? hh : ww);
      float c = fcos[src * 64 + j];
      float sn = fsin[src * 64 + j];
      float xr_ = y[2 * p], xim = y[2 * p + 1];
      y[2 * p] = xr_ * c - xim * sn;
      y[2 * p + 1] = xr_ * sn + xim * c;
    }
  }
  short8_t o;
#pragma unroll
  for (int i = 0; i < 8; ++i) o[i] = f2bf(y[i]);
  *(short8_t*)((short*)out + (size_t)row * DIMX + t * 8) = o;
}

// merged cross-attn RMS: rows [0,nq) from xq (stride DIMX) -> outq;
// rows [nq, nq+nk) from xkv (stride 2*DIMX) -> outk.  No RoPE.
__global__ __launch_bounds__(256) void rms_mix_kernel(
    const bf16* __restrict__ xq, const float* __restrict__ wq, bf16* __restrict__ outq,
    const bf16* __restrict__ xkv, const float* __restrict__ wk, bf16* __restrict__ outk,
    int nq) {
  int row = blockIdx.x;
  int t = threadIdx.x;
  const short* src;
  const float* w;
  short* dst;
  if (row < nq) {
    src = (const short*)xq + (size_t)row * DIMX;
    w = wq;
    dst = (short*)outq + (size_t)row * DIMX;
  } else {
    int r = row - nq;
    src = (const short*)xkv + (size_t)r * 2 * DIMX;
    w = wk;
    dst = (short*)outk + (size_t)r * DIMX;
  }
  short8_t xi = *(const short8_t*)(src + t * 8);
  float vv[8];
#pragma unroll
  for (int i = 0; i < 8; ++i) vv[i] = bf2f(xi[i]);
  float ss = 0.f;
#pragma unroll
  for (int i = 0; i < 8; ++i) ss += vv[i] * vv[i];
  __shared__ float red[4];
  ss = wred_sum(ss);
  int wid = t >> 6;
  if ((t & 63) == 0) red[wid] = ss;
  __syncthreads();
  float sumsq = red[0] + red[1] + red[2] + red[3];
  float rs = rsqrtf(sumsq * (1.f / DIMX) + LN_EPS);
  short8_t o;
#pragma unroll
  for (int i = 0; i < 8; ++i) o[i] = f2bf(vv[i] * rs * w[t * 8 + i]);
  *(short8_t*)(dst + t * 8) = o;
}

// ------------- 256x256 8-phase GEMM v3.1 (R11-proven, 16x16x32) -----
#define RDAe(dst, bufL, mh) { _Pragma("unroll") for (int mi = 0; mi < 4; ++mi) { \
    dst[mi][0] = *(const short8_t*)&AsF[aA[mi][0] + (mh) * 4096 + (bufL) * 16384]; \
    dst[mi][1] = *(const short8_t*)&AsF[aA[mi][1] + (mh) * 4096 + (bufL) * 16384]; } }
#define RDBe(dst, bufL, nh) { _Pragma("unroll") for (int nj = 0; nj < 2; ++nj) { \
    dst[nj][0] = *(const short8_t*)&BsF[aB[nj][0] + (nh) * 2048 + (bufL) * 16384]; \
    dst[nj][1] = *(const short8_t*)&BsF[aB[nj][1] + (nh) * 2048 + (bufL) * 16384]; } }
#define MMAQ(aS, bS, mh, nh) { _Pragma("unroll") for (int kq = 0; kq < 2; ++kq) \
    _Pragma("unroll") for (int mi = 0; mi < 4; ++mi) \
    _Pragma("unroll") for (int nj = 0; nj < 2; ++nj) \
      acc[(mh)*4+mi][(nh)*2+nj] = __builtin_amdgcn_mfma_f32_16x16x32_bf16( \
          aS[mi][kq], bS[nj][kq], acc[(mh)*4+mi][(nh)*2+nj], 0, 0, 0); }
#define STA(bufL, kkE, late) { _Pragma("unroll") for (int i = 0; i < 2; ++i) \
    gload16(Ap + gA[i][late] + (kkE), &AsF[ldsA[i][late] + (bufL) * 16384]); }
#define STB(bufL, kkE, late) { _Pragma("unroll") for (int i = 0; i < 2; ++i) \
    gload16(Bp + gB[i][late] + (kkE), &BsF[ldsB[i][late] + (bufL) * 16384]); }
#define BAR asm volatile("s_barrier" ::: "memory")
#define VMCNT(n) asm volatile("s_waitcnt vmcnt(" #n ")" ::: "memory")
#define SETPRIO(x) __builtin_amdgcn_s_setprio(x)

__global__ __launch_bounds__(512) void gemm256(
    const bf16* __restrict__ A, const bf16* __restrict__ Bt,
    const float* __restrict__ bias,
    float* outF, bf16* outB,
    const float* resid, const float* __restrict__ scale,
    int scstride, int rows_per_b, int gn, int N, int K,
    int klen, int nsplit, long long spoff, int mode) {
  __shared__ short AsF[2 * 16384];
  __shared__ short BsF[2 * 16384];
  int t = threadIdx.x, lane = t & 63, wv = t >> 6;
  int l15 = lane & 15, koff = lane >> 4;
  int wm = wv >> 2, wn = wv & 3;
  int nwgx = gridDim.x, ksp = 0, bid = blockIdx.x;
  if (nsplit == 2) { nwgx >>= 1; if (bid >= nwgx) { ksp = 1; bid -= nwgx; } }
  int cpx = nwgx >> 3;
  int swz = (bid & 7) * cpx + (bid >> 3);
  int by = swz / gn, bx = swz % gn;
  int m0 = by << 8, n0 = bx << 8;
  int kbeg = ksp * klen;

  f32x4 acc[8][4] = {};
  short8_t ae[4][2], al[4][2], be[2][2], bl[2][2];

  int aA[4][2], aB[2][2];
#pragma unroll
  for (int mi = 0; mi < 4; ++mi) {
    int r = wm * 128 + mi * 16 + l15;
#pragma unroll
    for (int kq = 0; kq < 2; ++kq)
      aA[mi][kq] = r * 64 + (((kq * 4 + koff) ^ (r & 7)) << 3);
  }
#pragma unroll
  for (int nj = 0; nj < 2; ++nj) {
    int r = wn * 64 + nj * 16 + l15;
#pragma unroll
    for (int kq = 0; kq < 2; ++kq)
      aB[nj][kq] = r * 64 + (((kq * 4 + koff) ^ (r & 7)) << 3);
  }

  int srcChunk = ((lane & 7) ^ (lane >> 3)) << 3;
  int rowInSlot = lane >> 3;
  const short* Ap = (const short*)A;
  const short* Bp = (const short*)Bt;
  size_t gA[2][2], gB[2][2];
  int ldsA[2][2], ldsB[2][2];
#pragma unroll
  for (int i = 0; i < 2; ++i) {
    int idx = i * 8 + wv;
#pragma unroll
    for (int late = 0; late < 2; ++late) {
      int slotA = ((idx >> 3) << 4) + (idx & 7) + late * 8;
      gA[i][late] = (size_t)(m0 + slotA * 8 + rowInSlot) * K + srcChunk;
      ldsA[i][late] = slotA << 9;
      int slotB = ((idx >> 2) << 3) + (idx & 3) + late * 4;
      gB[i][late] = (size_t)(n0 + slotB * 8 + rowInSlot) * K + srcChunk;
      ldsB[i][late] = slotB << 9;
    }
  }

  int NT = klen >> 6;
  STA(0, kbeg, 0); STB(0, kbeg, 0); STA(0, kbeg, 1); STB(0, kbeg, 1);
  STA(1, kbeg + 64, 0); STB(1, kbeg + 64, 0);
  VMCNT(4); BAR;

  for (int tt = 0; tt < NT; tt += 2) {
    int k1 = kbeg + (((tt + 1) < NT ? (tt + 1) : 0) << 6);
    int k2 = kbeg + (((tt + 2) < NT ? (tt + 2) : 0) << 6);
    int k3 = kbeg + (((tt + 3) < NT ? (tt + 3) : 0) << 6);
    RDAe(ae, 0, 0); RDBe(be, 0, 0);
    STA(1, k1, 1);
    BAR; SETPRIO(1); MMAQ(ae, be, 0, 0); SETPRIO(0); RDBe(bl, 0, 1); BAR;
    STB(1, k1, 1);
    BAR; SETPRIO(1); MMAQ(ae, bl, 0, 1); SETPRIO(0); RDAe(al, 0, 1); BAR;
    STA(0, k2, 0);
    BAR; SETPRIO(1); MMAQ(al, bl, 1, 1); SETPRIO(0); BAR;
    STB(0, k2, 0);
    BAR; SETPRIO(1); MMAQ(al, be, 1, 0); SETPRIO(0); VMCNT(4); BAR;
    RDAe(ae, 1, 0); RDBe(be, 1, 0);
    STA(0, k2, 1);
    BAR; SETPRIO(1); MMAQ(ae, be, 0, 0); SETPRIO(0); RDBe(bl, 1, 1); BAR;
    STB(0, k2, 1);
    BAR; SETPRIO(1); MMAQ(ae, bl, 0, 1); SETPRIO(0); RDAe(al, 1, 1); BAR;
    STA(1, k3, 0);
    BAR; SETPRIO(1); MMAQ(al, bl, 1, 1); SETPRIO(0); BAR;
    STB(1, k3, 0);
    BAR; SETPRIO(1); MMAQ(al, be, 1, 0); SETPRIO(0); VMCNT(4); BAR;
  }
  VMCNT(0);

  int mo = m0 + wm * 128, no = n0 + wn * 64;
  long long so = (long long)ksp * spoff;
#pragma unroll
  for (int mf = 0; mf < 8; ++mf)
#pragma unroll
    for (int nf = 0; nf < 4; ++nf) {
      int n = no + nf * 16 + l15;
      float bia = (mode == 5) ? 0.f : bias[n];
#pragma unroll
      for (int r = 0; r < 4; ++r) {
        int m = mo + mf * 16 + koff * 4 + r;
        float vv = acc[mf][nf][r] + bia;
        size_t idx = (size_t)m * N + n;
        if (mode == 1) {
          ((short*)outB)[idx] = f2bf(vv);
        } else if (mode == 2) {
          float u = 0.7978845608f * (vv + 0.044715f * vv * vv * vv);
          float g = vv / (1.f + exp2f(-2.88539009f * u));
          ((short*)outB)[idx] = f2bf(g);
        } else if (mode == 5) {
          ((short*)outB)[idx + so] = f2bf(vv);
        } else {
          float sc = scale ? scale[(size_t)(m / rows_per_b) * scstride + n] : 1.0f;
          outF[idx] = resid[idx] + vv * sc;
        }
      }
    }
}

// ---------------- 128x128 2-phase GEMM (proven R3) --------
__global__ __launch_bounds__(256) void gemm_bt(
    const bf16* __restrict__ A, const bf16* __restrict__ Bt,
    const float* __restrict__ bias,
    float* outF, bf16* outB,
    const float* resid, const float* __restrict__ scale,
    int scstride, int rows_per_b, int gn, int N, int K, int mode) {
  __shared__ short As[2][128 * 64];
  __shared__ short Bs[2][128 * 64];
  int t = threadIdx.x, lane = t & 63, wv = t >> 6;
  int nwg = gridDim.x, cpx = nwg >> 3;
  int swz = (blockIdx.x & 7) * cpx + (blockIdx.x >> 3);
  int by = swz / gn, bx = swz % gn;
  int m0 = by << 7, n0 = bx << 7;
  f32x4 acc[4][4] = {};
  int mo_l = (wv >> 1) << 6, no_l = (wv & 1) << 6;

  int srow[4], scol[4];
#pragma unroll
  for (int j = 0; j < 4; ++j) {
    srow[j] = wv * 32 + j * 8 + (lane >> 3);
    scol[j] = ((lane & 7) ^ (srow[j] & 7)) << 3;
  }
  const short* Ap = (const short*)A;
  const short* Bp = (const short*)Bt;

  int koff = lane >> 4;
  int rowA[4], rowB[4];
#pragma unroll
  for (int i = 0; i < 4; ++i) {
    rowA[i] = mo_l + i * 16 + (lane & 15);
    rowB[i] = no_l + i * 16 + (lane & 15);
  }

  auto stage = [&](int bufI, int kk) {
#pragma unroll
    for (int j = 0; j < 4; ++j) {
      gload16(Ap + (size_t)(m0 + srow[j]) * K + kk + scol[j],
              &As[bufI][(wv * 32 + j * 8) * 64]);
      gload16(Bp + (size_t)(n0 + srow[j]) * K + kk + scol[j],
              &Bs[bufI][(wv * 32 + j * 8) * 64]);
    }
  };

  stage(0, 0);
  __syncthreads();
  int cur = 0;
  for (int kk = 0; kk < K; kk += 64) {
    int nxt = cur ^ 1;
    if (kk + 64 < K) stage(nxt, kk + 64);
    short8_t af[2][4], bfv[2][4];
#pragma unroll
    for (int h = 0; h < 2; ++h)
#pragma unroll
      for (int i = 0; i < 4; ++i) {
        int cA = ((h * 4 + koff) ^ (rowA[i] & 7)) << 3;
        af[h][i] = *(const short8_t*)&As[cur][rowA[i] * 64 + cA];
        int cB = ((h * 4 + koff) ^ (rowB[i] & 7)) << 3;
        bfv[h][i] = *(const short8_t*)&Bs[cur][rowB[i] * 64 + cB];
      }
#pragma unroll
    for (int h = 0; h < 2; ++h)
#pragma unroll
      for (int mt = 0; mt < 4; ++mt)
#pragma unroll
        for (int nt = 0; nt < 4; ++nt)
          acc[mt][nt] = __builtin_amdgcn_mfma_f32_16x16x32_bf16(af[h][mt], bfv[h][nt], acc[mt][nt], 0, 0, 0);
    __syncthreads();
    cur = nxt;
  }

  int mo = m0 + mo_l, no = n0 + no_l;
#pragma unroll
  for (int mt = 0; mt < 4; ++mt)
#pragma unroll
    for (int nt = 0; nt < 4; ++nt) {
      int n = no + nt * 16 + (lane & 15);
      float bia = bias[n];
#pragma unroll
      for (int r = 0; r < 4; ++r) {
        int m = mo + mt * 16 + (lane >> 4) * 4 + r;
        float vv = acc[mt][nt][r] + bia;
        size_t idx = (size_t)m * N + n;
        if (mode == 1) {
          ((short*)outB)[idx] = f2bf(vv);
        } else if (mode == 2) {
          float g = 0.5f * vv * (1.f + tanhf(0.7978845608f * (vv + 0.044715f * vv * vv * vv)));
          ((short*)outB)[idx] = f2bf(g);
        } else {
          float sc = scale ? scale[(size_t)(m / rows_per_b) * scstride + n] : 1.0f;
          outF[idx] = resid[idx] + vv * sc;
        }
      }
    }
}

// Flash attention v5 (R13-proven): XCD swizzle, T14 async stage, defer-max,
// swizzled V^T, packed-dword P, log2 softmax, setprio.
__global__ __launch_bounds__(512) void attn_kernel(
    const bf16* __restrict__ q, const bf16* __restrict__ k,
    const bf16* __restrict__ v, bf16* __restrict__ y,
    int QL, int KVL, int qs, int ks, int vs, float scl) {
  __shared__ short Kt[64 * 136];
  __shared__ short Vt[128 * 72];
  __shared__ unsigned Pl[128 * 36];
  __shared__ float rl[8 * 16];
  __shared__ float ll[8 * 16];
  int t = threadIdx.x, lane = t & 63, wv = t >> 6;
  int l15 = lane & 15, koff = lane >> 4;
  int id = blockIdx.x;
  int c = id & 7, j = id >> 3;
  int bh = c * 4 + (j >> 4);
  int qx = j & 15;
  int b = bh / NHEADS, h = bh % NHEADS;
  int q0 = qx * 128 + wv * 16;
  const short* qp = (const short*)q;
  const short* kp = (const short*)k;
  const short* vp = (const short*)v;
  const float c1 = scl * 1.44269504088896f;
  short8_t qf[4];
  {
    size_t qbase = ((size_t)(b * QL) + q0 + l15) * qs + h * HDIM + koff * 8;
#pragma unroll
    for (int kc = 0; kc < 4; ++kc) qf[kc] = *(const short8_t*)(qp + qbase + kc * 32);
  }
  f32x4 o[8] = {};
  float m_run = -1e30f, l_run = 0.f;
  int strow = t >> 3, stcol = (t & 7) * 16;
  size_t kbase = (size_t)(b * KVL + strow) * ks + h * HDIM + stcol;
  size_t vbase = (size_t)(b * KVL + strow) * vs + h * HDIM + stcol;
  short8_t kreg[2], vreg[2];
  kreg[0] = *(const short8_t*)(kp + kbase);
  kreg[1] = *(const short8_t*)(kp + kbase + 8);
  vreg[0] = *(const short8_t*)(vp + vbase);
  vreg[1] = *(const short8_t*)(vp + vbase + 8);
  for (int kt0 = 0; kt0 < KVL; kt0 += 64) {
#pragma unroll
    for (int cc = 0; cc < 2; ++cc)
      *(short8_t*)&Kt[strow * 136 + stcol + cc * 8] = kreg[cc];
#pragma unroll
    for (int cc = 0; cc < 2; ++cc) {
#pragma unroll
      for (int e = 0; e < 8; ++e) {
        int d = stcol + cc * 8 + e;
        Vt[d * 72 + (strow ^ ((d >> 2) & 0x38))] = vreg[cc][e];
      }
    }
    if (kt0 + 64 < KVL) {
      size_t kb2 = kbase + (size_t)(kt0 + 64) * ks;
      size_t vb2 = vbase + (size_t)(kt0 + 64) * vs;
      kreg[0] = *(const short8_t*)(kp + kb2);
      kreg[1] = *(const short8_t*)(kp + kb2 + 8);
      vreg[0] = *(const short8_t*)(vp + vb2);
      vreg[1] = *(const short8_t*)(vp + vb2 + 8);
    }
    __syncthreads();
    f32x4 st[4];
    SETPRIO(1);
#pragma unroll
    for (int kt = 0; kt < 4; ++kt) {
      f32x4 aa = {0.f, 0.f, 0.f, 0.f};
#pragma unroll
      for (int kc = 0; kc < 4; ++kc) {
        short8_t kf = *(const short8_t*)&Kt[(kt * 16 + l15) * 136 + kc * 32 + koff * 8];
        aa = __builtin_amdgcn_mfma_f32_16x16x32_bf16(kf, qf[kc], aa, 0, 0, 0);
      }
      st[kt] = aa;
    }
    SETPRIO(0);
    float mk[4];
#pragma unroll
    for (int kt = 0; kt < 4; ++kt)
      mk[kt] = fmaxf(fmaxf(st[kt][0], st[kt][1]), fmaxf(st[kt][2], st[kt][3]));
    float mt_ = fmaxf(fmaxf(mk[0], mk[1]), fmaxf(mk[2], mk[3]));
    mt_ = fmaxf(mt_, __shfl_xor(mt_, 16, 64));
    mt_ = fmaxf(mt_, __shfl_xor(mt_, 32, 64));
    float mtc = mt_ * c1;
    bool nos = __all(mtc <= m_run + 8.0f);
    float m_new = nos ? m_run : fmaxf(m_run, mtc);
    float pk[4];
#pragma unroll
    for (int kt = 0; kt < 4; ++kt) {
#pragma unroll
      for (int r = 0; r < 4; ++r)
        st[kt][r] = exp2f(fmaf(st[kt][r], c1, -m_new));
      pk[kt] = (st[kt][0] + st[kt][1]) + (st[kt][2] + st[kt][3]);
    }
    float ps = (pk[0] + pk[1]) + (pk[2] + pk[3]);
    ps += __shfl_xor(ps, 16, 64);
    ps += __shfl_xor(ps, 32, 64);
    if (!nos) {
      float rfac = exp2f(m_run - m_new);
      l_run = l_run * rfac + ps;
      m_run = m_new;
      if (lane < 16) rl[wv * 16 + lane] = rfac;
      float rr[4];
#pragma unroll
      for (int r = 0; r < 4; ++r) rr[r] = rl[wv * 16 + koff * 4 + r];
#pragma unroll
      for (int dt = 0; dt < 8; ++dt)
#pragma unroll
        for (int r = 0; r < 4; ++r) o[dt][r] *= rr[r];
    } else {
      l_run += ps;
    }
#pragma unroll
    for (int kt = 0; kt < 4; ++kt)
#pragma unroll
      for (int rp = 0; rp < 2; ++rp) {
        unsigned lo = (unsigned short)f2bf(st[kt][2 * rp]);
        unsigned hi = (unsigned short)f2bf(st[kt][2 * rp + 1]);
        Pl[(wv * 16 + l15) * 36 + kt * 8 + koff * 2 + rp] = lo | (hi << 16);
      }
    SETPRIO(1);
#pragma unroll
    for (int kc2 = 0; kc2 < 2; ++kc2) {
      short8_t pa = *(const short8_t*)&Pl[(wv * 16 + l15) * 36 + kc2 * 16 + koff * 4];
#pragma unroll
      for (int dt = 0; dt < 8; ++dt) {
        int drow = dt * 16 + l15;
        int kv0 = (kc2 * 32 + koff * 8) ^ ((drow >> 2) & 0x38);
        short8_t vf = *(const short8_t*)&Vt[drow * 72 + kv0];
        o[dt] = __builtin_amdgcn_mfma_f32_16x16x32_bf16(pa, vf, o[dt], 0, 0, 0);
      }
    }
    SETPRIO(0);
    __syncthreads();
  }
  if (lane < 16) ll[wv * 16 + lane] = 1.f / l_run;
  float li[4];
#pragma unroll
  for (int r = 0; r < 4; ++r) li[r] = ll[wv * 16 + koff * 4 + r];
  short* yp = (short*)y;
#pragma unroll
  for (int dt = 0; dt < 8; ++dt)
#pragma unroll
    for (int r = 0; r < 4; ++r) {
      int qq = q0 + koff * 4 + r;
      int d = dt * 16 + l15;
      yp[((size_t)(b * QL) + qq) * DIMX + h * HDIM + d] = f2bf(o[dt][r] * li[r]);
    }
}

// ws layout (bytes)
#define OFF_EM    0ull
#define OFF_BQKV  (512ull << 10)
#define OFF_BCKV  (560ull << 10)
#define OFF_XN    (1ull << 20)
#define OFF_QKB   (17ull << 20)   // fused qk: 32 MB (17..49)
#define OFF_VB2   (49ull << 20)   // self-attn v: 16 MB (49..65)
#define OFF_CAQ   (17ull << 20)
#define OFF_KV    (33ull << 20)
#define OFF_QB    (65ull << 20)
#define OFF_KB    (81ull << 20)
#define OFF_YB    (97ull << 20)
#define OFF_CTX   (113ull << 20)
#define OFF_WBUF  (117ull << 20)
#define OFF_HB    (17ull << 20)   // FFN hidden 64 MB (17..81)
#define OFF_PS    (81ull << 20)   // FFN2 partials 2x16 MB (81..113) - no hb overlap

extern "C" void kernel_launch(void* const* d_in, const int* in_sizes, int n_in,
                              void* d_out, int out_size, void* d_ws, size_t ws_size,
                              hipStream_t stream) {
  const float* x       = (const float*)d_in[0];
  const float* e       = (const float*)d_in[1];
  const float* context = (const float*)d_in[2];
  const float* fcos    = (const float*)d_in[3];
  const float* fsin    = (const float*)d_in[4];
  const float* modu    = (const float*)d_in[5];
  const float* sa_wq = (const float*)d_in[6];  const float* sa_bq = (const float*)d_in[7];
  const float* sa_wk = (const float*)d_in[8];  const float* sa_bk = (const float*)d_in[9];
  const float* sa_wv = (const float*)d_in[10]; const float* sa_bv = (const float*)d_in[11];
  const float* sa_wo = (const float*)d_in[12]; const float* sa_bo = (const float*)d_in[13];
  const float* sa_nq = (const float*)d_in[14]; const float* sa_nk = (const float*)d_in[15];
  const float* ca_wq = (const float*)d_in[16]; const float* ca_bq = (const float*)d_in[17];
  const float* ca_wk = (const float*)d_in[18]; const float* ca_bk = (const float*)d_in[19];
  const float* ca_wv = (const float*)d_in[20]; const float* ca_bv = (const float*)d_in[21];
  const float* ca_wo = (const float*)d_in[22]; const float* ca_bo = (const float*)d_in[23];
  const float* ca_nq = (const float*)d_in[24]; const float* ca_nk = (const float*)d_in[25];
  const float* n3_w  = (const float*)d_in[26]; const float* n3_b  = (const float*)d_in[27];
  const float* f_w1  = (const float*)d_in[28]; const float* f_b1  = (const float*)d_in[29];
  const float* f_w2  = (const float*)d_in[30]; const float* f_b2  = (const float*)d_in[31];

  char* ws = (char*)d_ws;
  float* em   = (float*)(ws + OFF_EM);
  float* bqkv = (float*)(ws + OFF_BQKV);
  float* bckv = (float*)(ws + OFF_BCKV);
  bf16* xn    = (bf16*)(ws + OFF_XN);
  bf16* qkb   = (bf16*)(ws + OFF_QKB);
  bf16* vb2   = (bf16*)(ws + OFF_VB2);
  bf16* caqb  = (bf16*)(ws + OFF_CAQ);
  bf16* kvb   = (bf16*)(ws + OFF_KV);
  bf16* qb    = (bf16*)(ws + OFF_QB);
  bf16* kb    = (bf16*)(ws + OFF_KB);
  bf16* yb    = (bf16*)(ws + OFF_YB);
  bf16* ctxb  = (bf16*)(ws + OFF_CTX);
  bf16* wbuf  = (bf16*)(ws + OFF_WBUF);
  bf16* hb    = (bf16*)(ws + OFF_HB);
  bf16* ps    = (bf16*)(ws + OFF_PS);
  float* xw   = (float*)d_out;

  const int M = BSZ * SLEN;
  const int MC = BSZ * CTXL;
  const float scl = 0.08838834764831845f;
  const size_t WSTRIDE = (size_t)DIMX * DIMX;

#define GEMM256(Am, Bt, Md, Nd, Kd, bias, oF, oB, res, sc, scs, rpb, mode) \
  gemm256<<<((Md) / 256) * ((Nd) / 256), 512, 0, stream>>>(Am, Bt, bias, oF, oB, res, sc, \
                                                           scs, rpb, (Nd) / 256, Nd, Kd, Kd, 1, 0ll, mode)
#define GEMM128(Am, Bt, Md, Nd, Kd, bias, oF, oB, res, sc, scs, rpb, mode) \
  gemm_bt<<<((Md) / 128) * ((Nd) / 128), 256, 0, stream>>>(Am, Bt, bias, oF, oB, res, sc, scs, rpb, (Nd) / 128, Nd, Kd, mode)

  prep_kernel<<<(BSZ * 6 * DIMX + 5 * DIMX + MC * DIMX / 8 + 255) / 256, 256, 0, stream>>>(
      e, modu, em, sa_bq, sa_bk, sa_bv, bqkv, ca_bk, ca_bv, bckv, context, ctxb);

  // --- self attention ---
  ln_kernel<<<M, 256, 0, stream>>>(x, em + 1 * DIMX, em + 0 * DIMX, 6 * DIMX, 1.0f, SLEN, xn);

  transpose_w4<<<dim3(DIMX / 64, DIMX / 64, 4), 256, 0, stream>>>(
      sa_wq, sa_wk, sa_wv, sa_wo, wbuf, DIMX, DIMX);

  // fused QK: N=4096 -> 256 blocks (1 exact round); V: 512 blocks (2 rounds)
  GEMM256(xn, wbuf, M, 2 * DIMX, DIMX, bqkv, nullptr, qkb, nullptr, nullptr, 0, 1, 1);
  GEMM128(xn, wbuf + 2 * WSTRIDE, M, DIMX, DIMX, sa_bv, nullptr, vb2, nullptr, nullptr, 0, 1, 1);

  rms_rope_kernel<<<dim3(M, 2), 256, 0, stream>>>(qkb, 2 * DIMX, sa_nq, sa_nk,
                                                  fcos, fsin, 1, qb, kb);

  attn_kernel<<<512, 512, 0, stream>>>(qb, kb, vb2, yb, SLEN, SLEN, DIMX, DIMX, DIMX, scl);

  GEMM128(yb, wbuf + 3 * WSTRIDE, M, DIMX, DIMX, sa_bo, xw, nullptr,
          x, em + 2 * DIMX, 6 * DIMX, SLEN, 3);

  // --- cross attention ---
  ln_kernel<<<M, 256, 0, stream>>>(xw, n3_w, n3_b, 0, 0.0f, SLEN, xn);

  transpose_w4<<<dim3(DIMX / 64, DIMX / 64, 4), 256, 0, stream>>>(
      ca_wq, ca_wk, ca_wv, ca_wo, wbuf, DIMX, DIMX);

  GEMM128(xn, wbuf, M, DIMX, DIMX, ca_bq, nullptr, caqb, nullptr, nullptr, 0, 1, 1);
  GEMM128(ctxb, wbuf + WSTRIDE, MC, 2 * DIMX, DIMX, bckv, nullptr, kvb,
          nullptr, nullptr, 0, 1, 1);

  rms_mix_kernel<<<M + MC, 256, 0, stream>>>(caqb, ca_nq, qb, kvb, ca_nk, kb, M);

  attn_kernel<<<512, 512, 0, stream>>>(qb, kb, (bf16*)((short*)kvb + DIMX), yb,
                                       SLEN, CTXL, DIMX, DIMX, 2 * DIMX, scl);

  GEMM128(yb, wbuf + 3 * WSTRIDE, M, DIMX, DIMX, ca_bo, xw, nullptr,
          xw, nullptr, 0, SLEN, 3);

  // --- FFN ---
  ln_kernel<<<M, 256, 0, stream>>>(xw, em + 4 * DIMX, em + 3 * DIMX, 6 * DIMX, 1.0f, SLEN, xn);

  transpose_w4<<<dim3(FFND / 64, DIMX / 64, 1), 256, 0, stream>>>(
      f_w1, nullptr, nullptr, nullptr, wbuf, DIMX, FFND);
  GEMM256(xn, wbuf, M, FFND, DIMX, f_b1, nullptr, hb, nullptr, nullptr, 0, 1, 2);

  transpose_w4<<<dim3(DIMX / 64, FFND / 64, 1), 256, 0, stream>>>(
      f_w2, nullptr, nullptr, nullptr, wbuf, FFND, DIMX);
  gemm256<<<2 * (M / 256) * (DIMX / 256), 512, 0, stream>>>(
      hb, wbuf, f_b2, nullptr, ps, nullptr, nullptr, 0, 1, DIMX / 256, DIMX,
      FFND, FFND / 2, 2, (long long)M * DIMX, 5);
  combine_kernel<<<M * DIMX / 8 / 256, 256, 0, stream>>>(
      ps, ps + (size_t)M * DIMX, f_b2, xw, em + 5 * DIMX, 6 * DIMX, SLEN, xw, DIMX);
}

// Round 16
// 950.750 us; speedup vs baseline: 1.0407x; 1.0123x over previous
//
#include <hip/hip_runtime.h>
#include <hip/hip_bf16.h>
#include <math.h>

#define DIMX 2048
#define SLEN 2048
#define BSZ 2
#define NHEADS 16
#define HDIM 128
#define FFND 8192
#define CTXL 512
#define LN_EPS 1e-6f

typedef __attribute__((ext_vector_type(8))) short short8_t;
typedef __attribute__((ext_vector_type(4))) short short4_t;
typedef __attribute__((ext_vector_type(4))) float f32x4;
typedef __hip_bfloat16 bf16;

__device__ __forceinline__ short f2bf(float f) {
  union { float f; unsigned u; } v; v.f = f;
  return (short)((v.u + 0x7FFFu + ((v.u >> 16) & 1u)) >> 16);
}
__device__ __forceinline__ float bf2f(short s) {
  union { unsigned u; float f; } v; v.u = ((unsigned)(unsigned short)s) << 16;
  return v.f;
}

__device__ __forceinline__ void gload16(const void* g, void* l) {
  __builtin_amdgcn_global_load_lds(
      (const __attribute__((address_space(1))) unsigned int*)g,
      (__attribute__((address_space(3))) unsigned int*)l, 16, 0, 0);
}

__device__ __forceinline__ float wred_sum(float v) {
#pragma unroll
  for (int o = 32; o > 0; o >>= 1) v += __shfl_xor(v, o, 64);
  return v;
}

// fused: em add + bias packs (qkv 3-wide; ckv 2-wide) + context fp32->bf16
__global__ void prep_kernel(const float* __restrict__ e, const float* __restrict__ mod,
                            float* __restrict__ em,
                            const float* __restrict__ sa_bq, const float* __restrict__ sa_bk,
                            const float* __restrict__ sa_bv, float* __restrict__ bqkv,
                            const float* __restrict__ ca_bk, const float* __restrict__ ca_bv,
                            float* __restrict__ bckv,
                            const float* __restrict__ ctx, bf16* __restrict__ ctxb) {
  int i = blockIdx.x * 256 + threadIdx.x;
  if (i < BSZ * 6 * DIMX) { em[i] = e[i] + mod[i % (6 * DIMX)]; return; }
  i -= BSZ * 6 * DIMX;
  if (i < 3 * DIMX) {
    bqkv[i] = (i < DIMX) ? sa_bq[i] : (i < 2 * DIMX) ? sa_bk[i - DIMX] : sa_bv[i - 2 * DIMX];
    return;
  }
  i -= 3 * DIMX;
  if (i < 2 * DIMX) { bckv[i] = (i < DIMX) ? ca_bk[i] : ca_bv[i - DIMX]; return; }
  i -= 2 * DIMX;
  if (i < BSZ * CTXL * DIMX / 8) {
    float4 a = *(const float4*)(ctx + (size_t)i * 8);
    float4 b = *(const float4*)(ctx + (size_t)i * 8 + 4);
    float fv[8] = {a.x, a.y, a.z, a.w, b.x, b.y, b.z, b.w};
    short8_t o;
#pragma unroll
    for (int j = 0; j < 8; ++j) o[j] = f2bf(fv[j]);
    *(short8_t*)((short*)ctxb + (size_t)i * 8) = o;
  }
}

// out = resid + (p0 + p1 + bias) * scale   (FFN2 split-K combine)
__global__ __launch_bounds__(256) void combine_kernel(
    const bf16* __restrict__ p0, const bf16* __restrict__ p1,
    const float* __restrict__ bias, const float* __restrict__ resid,
    const float* __restrict__ scale, int scstride, int rows_per_b,
    float* __restrict__ out, int N) {
  int i8 = blockIdx.x * 256 + threadIdx.x;
  size_t base = (size_t)i8 * 8;
  int n = (int)(base % N);
  int m = (int)(base / N);
  int b = m / rows_per_b;
  short8_t a = *(const short8_t*)((const short*)p0 + base);
  short8_t c = *(const short8_t*)((const short*)p1 + base);
  const float* bi = bias + n;
  const float* sc = scale + (size_t)b * scstride + n;
  const float* rs = resid + base;
  float* o = out + base;
#pragma unroll
  for (int j = 0; j < 8; ++j)
    o[j] = rs[j] + (bf2f(a[j]) + bf2f(c[j]) + bi[j]) * sc[j];
}

// batched: up to 4 weights [K][N] -> Wt bf16 rows [z*N + n][K]
__global__ __launch_bounds__(256) void transpose_w4(
    const float* s0, const float* s1, const float* s2, const float* s3,
    bf16* __restrict__ Wt, int K, int N) {
  __shared__ short tile[64 * 68];
  const float* W = (blockIdx.z == 0) ? s0 : (blockIdx.z == 1) ? s1
                   : (blockIdx.z == 2) ? s2 : s3;
  int noff = blockIdx.z * N;
  int k0 = blockIdx.y << 6, n0 = blockIdx.x << 6;
  int t = threadIdx.x;
#pragma unroll
  for (int p = 0; p < 4; ++p) {
    int lin = p * 1024 + t * 4;
    int kr = lin >> 6, nc = lin & 63;
    float4 f = *(const float4*)(W + (size_t)(k0 + kr) * N + n0 + nc);
    tile[(nc + 0) * 68 + kr] = f2bf(f.x);
    tile[(nc + 1) * 68 + kr] = f2bf(f.y);
    tile[(nc + 2) * 68 + kr] = f2bf(f.z);
    tile[(nc + 3) * 68 + kr] = f2bf(f.w);
  }
  __syncthreads();
#pragma unroll
  for (int p = 0; p < 4; ++p) {
    int lin = p * 1024 + t * 4;
    int nr = lin >> 6, kc = lin & 63;
    short4_t s = *(const short4_t*)&tile[nr * 68 + kc];
    *(short4_t*)((short*)Wt + (size_t)(noff + n0 + nr) * K + k0 + kc) = s;
  }
}

__global__ __launch_bounds__(256) void ln_kernel(
    const float* __restrict__ x, const float* __restrict__ gamma,
    const float* __restrict__ beta, int gbstride, float addone,
    int rows_per_b, bf16* __restrict__ out) {
  int row = blockIdx.x;
  int t = threadIdx.x;
  const float* xr = x + (size_t)row * DIMX;
  float4 v0 = *(const float4*)(xr + t * 8);
  float4 v1 = *(const float4*)(xr + t * 8 + 4);
  float vv[8] = {v0.x, v0.y, v0.z, v0.w, v1.x, v1.y, v1.z, v1.w};
  float s = 0.f, ss = 0.f;
#pragma unroll
  for (int i = 0; i < 8; ++i) { s += vv[i]; ss += vv[i] * vv[i]; }
  __shared__ float red[8];
  s = wred_sum(s); ss = wred_sum(ss);
  int wid = t >> 6;
  if ((t & 63) == 0) { red[wid] = s; red[4 + wid] = ss; }
  __syncthreads();
  float sum = red[0] + red[1] + red[2] + red[3];
  float sumsq = red[4] + red[5] + red[6] + red[7];
  float mean = sum * (1.f / DIMX);
  float var = sumsq * (1.f / DIMX) - mean * mean;
  float rs = rsqrtf(var + LN_EPS);
  int b = row / rows_per_b;
  const float* g = gamma + (size_t)b * gbstride;
  const float* be = beta + (size_t)b * gbstride;
  short8_t o;
#pragma unroll
  for (int i = 0; i < 8; ++i) {
    int d = t * 8 + i;
    float y = (vv[i] - mean) * rs;
    o[i] = f2bf(y * (addone + g[d]) + be[d]);
  }
  *(short8_t*)((short*)out + (size_t)row * DIMX + t * 8) = o;
}

// RMSNorm+RoPE; blockIdx.y selects (w0,out0) vs (w1,out1), src offset y*DIMX
__global__ __launch_bounds__(256) void rms_rope_kernel(
    const bf16* __restrict__ x, int xstride, const float* __restrict__ w0,
    const float* __restrict__ w1, const float* __restrict__ fcos,
    const float* __restrict__ fsin, int do_rope,
    bf16* __restrict__ out0, bf16* __restrict__ out1) {
  int row = blockIdx.x;
  int t = threadIdx.x;
  int sel = blockIdx.y;
  const float* w = sel ? w1 : w0;
  bf16* out = sel ? out1 : out0;
  short8_t xi = *(const short8_t*)((const short*)x + (size_t)row * xstride + sel * DIMX + t * 8);
  float vv[8];
#pragma unroll
  for (int i = 0; i < 8; ++i) vv[i] = bf2f(xi[i]);
  float ss = 0.f;
#pragma unroll
  for (int i = 0; i < 8; ++i) ss += vv[i] * vv[i];
  __shared__ float red[4];
  ss = wred_sum(ss);
  int wid = t >> 6;
  if ((t & 63) == 0) red[wid] = ss;
  __syncthreads();
  float sumsq = red[0] + red[1] + red[2] + red[3];
  float rs = rsqrtf(sumsq * (1.f / DIMX) + LN_EPS);
  float y[8];
#pragma unroll
  for (int i = 0; i < 8; ++i) y[i] = vv[i] * rs * w[t * 8 + i];
  if (do_rope) {
    int s = row % SLEN;
    int f = s >> 8, hh = (s >> 4) & 15, ww = s & 15;
    int jb = ((t * 8) % HDIM) >> 1;
#pragma unroll
    for (int p = 0; p < 4; ++p) {
      int j = jb + p;
      int src = (j < 22) ? f : ((j < 43) ? hh : ww);
      float c = fcos[src * 64 + j];
      float sn = fsin[src * 64 + j];
      float xr_ = y[2 * p], xim = y[2 * p + 1];
      y[2 * p] = xr_ * c - xim * sn;
      y[2 * p + 1] = xr_ * sn + xim * c;
    }
  }
  short8_t o;
#pragma unroll
  for (int i = 0; i < 8; ++i) o[i] = f2bf(y[i]);
  *(short8_t*)((short*)out + (size_t)row * DIMX + t * 8) = o;
}

// merged cross-attn RMS: rows [0,nq) from xq (stride DIMX) -> outq;
// rows [nq, nq+nk) from xkv (stride 2*DIMX) -> outk.  No RoPE.
__global__ __launch_bounds__(256) void rms_mix_kernel(
    const bf16* __restrict__ xq, const float* __restrict__ wq, bf16* __restrict__ outq,
    const bf16* __restrict__ xkv, const float* __restrict__ wk, bf16* __restrict__ outk,
    int nq) {
  int row = blockIdx.x;
  int t = threadIdx.x;
  const short* src;
  const float* w;
  short* dst;
  if (row < nq) {
    src = (const short*)xq + (size_t)row * DIMX;
    w = wq;
    dst = (short*)outq + (size_t)row * DIMX;
  } else {
    int r = row - nq;
    src = (const short*)xkv + (size_t)r * 2 * DIMX;
    w = wk;
    dst = (short*)outk + (size_t)r * DIMX;
  }
  short8_t xi = *(const short8_t*)(src + t * 8);
  float vv[8];
#pragma unroll
  for (int i = 0; i < 8; ++i) vv[i] = bf2f(xi[i]);
  float ss = 0.f;
#pragma unroll
  for (int i = 0; i < 8; ++i) ss += vv[i] * vv[i];
  __shared__ float red[4];
  ss = wred_sum(ss);
  int wid = t >> 6;
  if ((t & 63) == 0) red[wid] = ss;
  __syncthreads();
  float sumsq = red[0] + red[1] + red[2] + red[3];
  float rs = rsqrtf(sumsq * (1.f / DIMX) + LN_EPS);
  short8_t o;
#pragma unroll
  for (int i = 0; i < 8; ++i) o[i] = f2bf(vv[i] * rs * w[t * 8 + i]);
  *(short8_t*)(dst + t * 8) = o;
}

// ------------- 256x256 8-phase GEMM v3.1 (R11-proven, 16x16x32) -----
#define RDAe(dst, bufL, mh) { _Pragma("unroll") for (int mi = 0; mi < 4; ++mi) { \
    dst[mi][0] = *(const short8_t*)&AsF[aA[mi][0] + (mh) * 4096 + (bufL) * 16384]; \
    dst[mi][1] = *(const short8_t*)&AsF[aA[mi][1] + (mh) * 4096 + (bufL) * 16384]; } }
#define RDBe(dst, bufL, nh) { _Pragma("unroll") for (int nj = 0; nj < 2; ++nj) { \
    dst[nj][0] = *(const short8_t*)&BsF[aB[nj][0] + (nh) * 2048 + (bufL) * 16384]; \
    dst[nj][1] = *(const short8_t*)&BsF[aB[nj][1] + (nh) * 2048 + (bufL) * 16384]; } }
#define MMAQ(aS, bS, mh, nh) { _Pragma("unroll") for (int kq = 0; kq < 2; ++kq) \
    _Pragma("unroll") for (int mi = 0; mi < 4; ++mi) \
    _Pragma("unroll") for (int nj = 0; nj < 2; ++nj) \
      acc[(mh)*4+mi][(nh)*2+nj] = __builtin_amdgcn_mfma_f32_16x16x32_bf16( \
          aS[mi][kq], bS[nj][kq], acc[(mh)*4+mi][(nh)*2+nj], 0, 0, 0); }
#define STA(bufL, kkE, late) { _Pragma("unroll") for (int i = 0; i < 2; ++i) \
    gload16(Ap + gA[i][late] + (kkE), &AsF[ldsA[i][late] + (bufL) * 16384]); }
#define STB(bufL, kkE, late) { _Pragma("unroll") for (int i = 0; i < 2; ++i) \
    gload16(Bp + gB[i][late] + (kkE), &BsF[ldsB[i][late] + (bufL) * 16384]); }
#define BAR asm volatile("s_barrier" ::: "memory")
#define VMCNT(n) asm volatile("s_waitcnt vmcnt(" #n ")" ::: "memory")
#define SETPRIO(x) __builtin_amdgcn_s_setprio(x)

__global__ __launch_bounds__(512) void gemm256(
    const bf16* __restrict__ A, const bf16* __restrict__ Bt,
    const float* __restrict__ bias,
    float* outF, bf16* outB,
    const float* resid, const float* __restrict__ scale,
    int scstride, int rows_per_b, int gn, int N, int K,
    int klen, int nsplit, long long spoff, int mode) {
  __shared__ short AsF[2 * 16384];
  __shared__ short BsF[2 * 16384];
  int t = threadIdx.x, lane = t & 63, wv = t >> 6;
  int l15 = lane & 15, koff = lane >> 4;
  int wm = wv >> 2, wn = wv & 3;
  int nwgx = gridDim.x, ksp = 0, bid = blockIdx.x;
  if (nsplit == 2) { nwgx >>= 1; if (bid >= nwgx) { ksp = 1; bid -= nwgx; } }
  int cpx = nwgx >> 3;
  int swz = (bid & 7) * cpx + (bid >> 3);
  int by = swz / gn, bx = swz % gn;
  int m0 = by << 8, n0 = bx << 8;
  int kbeg = ksp * klen;

  f32x4 acc[8][4] = {};
  short8_t ae[4][2], al[4][2], be[2][2], bl[2][2];

  int aA[4][2], aB[2][2];
#pragma unroll
  for (int mi = 0; mi < 4; ++mi) {
    int r = wm * 128 + mi * 16 + l15;
#pragma unroll
    for (int kq = 0; kq < 2; ++kq)
      aA[mi][kq] = r * 64 + (((kq * 4 + koff) ^ (r & 7)) << 3);
  }
#pragma unroll
  for (int nj = 0; nj < 2; ++nj) {
    int r = wn * 64 + nj * 16 + l15;
#pragma unroll
    for (int kq = 0; kq < 2; ++kq)
      aB[nj][kq] = r * 64 + (((kq * 4 + koff) ^ (r & 7)) << 3);
  }

  int srcChunk = ((lane & 7) ^ (lane >> 3)) << 3;
  int rowInSlot = lane >> 3;
  const short* Ap = (const short*)A;
  const short* Bp = (const short*)Bt;
  size_t gA[2][2], gB[2][2];
  int ldsA[2][2], ldsB[2][2];
#pragma unroll
  for (int i = 0; i < 2; ++i) {
    int idx = i * 8 + wv;
#pragma unroll
    for (int late = 0; late < 2; ++late) {
      int slotA = ((idx >> 3) << 4) + (idx & 7) + late * 8;
      gA[i][late] = (size_t)(m0 + slotA * 8 + rowInSlot) * K + srcChunk;
      ldsA[i][late] = slotA << 9;
      int slotB = ((idx >> 2) << 3) + (idx & 3) + late * 4;
      gB[i][late] = (size_t)(n0 + slotB * 8 + rowInSlot) * K + srcChunk;
      ldsB[i][late] = slotB << 9;
    }
  }

  int NT = klen >> 6;
  STA(0, kbeg, 0); STB(0, kbeg, 0); STA(0, kbeg, 1); STB(0, kbeg, 1);
  STA(1, kbeg + 64, 0); STB(1, kbeg + 64, 0);
  VMCNT(4); BAR;

  for (int tt = 0; tt < NT; tt += 2) {
    int k1 = kbeg + (((tt + 1) < NT ? (tt + 1) : 0) << 6);
    int k2 = kbeg + (((tt + 2) < NT ? (tt + 2) : 0) << 6);
    int k3 = kbeg + (((tt + 3) < NT ? (tt + 3) : 0) << 6);
    RDAe(ae, 0, 0); RDBe(be, 0, 0);
    STA(1, k1, 1);
    BAR; SETPRIO(1); MMAQ(ae, be, 0, 0); SETPRIO(0); RDBe(bl, 0, 1); BAR;
    STB(1, k1, 1);
    BAR; SETPRIO(1); MMAQ(ae, bl, 0, 1); SETPRIO(0); RDAe(al, 0, 1); BAR;
    STA(0, k2, 0);
    BAR; SETPRIO(1); MMAQ(al, bl, 1, 1); SETPRIO(0); BAR;
    STB(0, k2, 0);
    BAR; SETPRIO(1); MMAQ(al, be, 1, 0); SETPRIO(0); VMCNT(4); BAR;
    RDAe(ae, 1, 0); RDBe(be, 1, 0);
    STA(0, k2, 1);
    BAR; SETPRIO(1); MMAQ(ae, be, 0, 0); SETPRIO(0); RDBe(bl, 1, 1); BAR;
    STB(0, k2, 1);
    BAR; SETPRIO(1); MMAQ(ae, bl, 0, 1); SETPRIO(0); RDAe(al, 1, 1); BAR;
    STA(1, k3, 0);
    BAR; SETPRIO(1); MMAQ(al, bl, 1, 1); SETPRIO(0); BAR;
    STB(1, k3, 0);
    BAR; SETPRIO(1); MMAQ(al, be, 1, 0); SETPRIO(0); VMCNT(4); BAR;
  }
  VMCNT(0);

  int mo = m0 + wm * 128, no = n0 + wn * 64;
  long long so = (long long)ksp * spoff;
#pragma unroll
  for (int mf = 0; mf < 8; ++mf)
#pragma unroll
    for (int nf = 0; nf < 4; ++nf) {
      int n = no + nf * 16 + l15;
      float bia = (mode == 5) ? 0.f : bias[n];
#pragma unroll
      for (int r = 0; r < 4; ++r) {
        int m = mo + mf * 16 + koff * 4 + r;
        float vv = acc[mf][nf][r] + bia;
        size_t idx = (size_t)m * N + n;
        if (mode == 1) {
          ((short*)outB)[idx] = f2bf(vv);
        } else if (mode == 2) {
          float u = 0.7978845608f * (vv + 0.044715f * vv * vv * vv);
          float g = vv / (1.f + exp2f(-2.88539009f * u));
          ((short*)outB)[idx] = f2bf(g);
        } else if (mode == 5) {
          ((short*)outB)[idx + so] = f2bf(vv);
        } else {
          float sc = scale ? scale[(size_t)(m / rows_per_b) * scstride + n] : 1.0f;
          outF[idx] = resid[idx] + vv * sc;
        }
      }
    }
}

// ---------------- 128x128 2-phase GEMM (proven R3) --------
__global__ __launch_bounds__(256) void gemm_bt(
    const bf16* __restrict__ A, const bf16* __restrict__ Bt,
    const float* __restrict__ bias,
    float* outF, bf16* outB,
    const float* resid, const float* __restrict__ scale,
    int scstride, int rows_per_b, int gn, int N, int K, int mode) {
  __shared__ short As[2][128 * 64];
  __shared__ short Bs[2][128 * 64];
  int t = threadIdx.x, lane = t & 63, wv = t >> 6;
  int nwg = gridDim.x, cpx = nwg >> 3;
  int swz = (blockIdx.x & 7) * cpx + (blockIdx.x >> 3);
  int by = swz / gn, bx = swz % gn;
  int m0 = by << 7, n0 = bx << 7;
  f32x4 acc[4][4] = {};
  int mo_l = (wv >> 1) << 6, no_l = (wv & 1) << 6;

  int srow[4], scol[4];
#pragma unroll
  for (int j = 0; j < 4; ++j) {
    srow[j] = wv * 32 + j * 8 + (lane >> 3);
    scol[j] = ((lane & 7) ^ (srow[j] & 7)) << 3;
  }
  const short* Ap = (const short*)A;
  const short* Bp = (const short*)Bt;

  int koff = lane >> 4;
  int rowA[4], rowB[4];
#pragma unroll
  for (int i = 0; i < 4; ++i) {
    rowA[i] = mo_l + i * 16 + (lane & 15);
    rowB[i] = no_l + i * 16 + (lane & 15);
  }

  auto stage = [&](int bufI, int kk) {
#pragma unroll
    for (int j = 0; j < 4; ++j) {
      gload16(Ap + (size_t)(m0 + srow[j]) * K + kk + scol[j],
              &As[bufI][(wv * 32 + j * 8) * 64]);
      gload16(Bp + (size_t)(n0 + srow[j]) * K + kk + scol[j],
              &Bs[bufI][(wv * 32 + j * 8) * 64]);
    }
  };

  stage(0, 0);
  __syncthreads();
  int cur = 0;
  for (int kk = 0; kk < K; kk += 64) {
    int nxt = cur ^ 1;
    if (kk + 64 < K) stage(nxt, kk + 64);
    short8_t af[2][4], bfv[2][4];
#pragma unroll
    for (int h = 0; h < 2; ++h)
#pragma unroll
      for (int i = 0; i < 4; ++i) {
        int cA = ((h * 4 + koff) ^ (rowA[i] & 7)) << 3;
        af[h][i] = *(const short8_t*)&As[cur][rowA[i] * 64 + cA];
        int cB = ((h * 4 + koff) ^ (rowB[i] & 7)) << 3;
        bfv[h][i] = *(const short8_t*)&Bs[cur][rowB[i] * 64 + cB];
      }
#pragma unroll
    for (int h = 0; h < 2; ++h)
#pragma unroll
      for (int mt = 0; mt < 4; ++mt)
#pragma unroll
        for (int nt = 0; nt < 4; ++nt)
          acc[mt][nt] = __builtin_amdgcn_mfma_f32_16x16x32_bf16(af[h][mt], bfv[h][nt], acc[mt][nt], 0, 0, 0);
    __syncthreads();
    cur = nxt;
  }

  int mo = m0 + mo_l, no = n0 + no_l;
#pragma unroll
  for (int mt = 0; mt < 4; ++mt)
#pragma unroll
    for (int nt = 0; nt < 4; ++nt) {
      int n = no + nt * 16 + (lane & 15);
      float bia = bias[n];
#pragma unroll
      for (int r = 0; r < 4; ++r) {
        int m = mo + mt * 16 + (lane >> 4) * 4 + r;
        float vv = acc[mt][nt][r] + bia;
        size_t idx = (size_t)m * N + n;
        if (mode == 1) {
          ((short*)outB)[idx] = f2bf(vv);
        } else if (mode == 2) {
          float g = 0.5f * vv * (1.f + tanhf(0.7978845608f * (vv + 0.044715f * vv * vv * vv)));
          ((short*)outB)[idx] = f2bf(g);
        } else {
          float sc = scale ? scale[(size_t)(m / rows_per_b) * scstride + n] : 1.0f;
          outF[idx] = resid[idx] + vv * sc;
        }
      }
    }
}

// dual-segment 128x128 2-phase GEMM (mode 1 only): bid<nwg1 -> set 1, else set 2.
// Fills the machine when one segment alone is a fractional residency round.
__global__ __launch_bounds__(256) void gemm_bt_dual(
    const bf16* A1, const bf16* Bt1, const float* bias1, bf16* out1, int N1, int gn1, int nwg1,
    const bf16* A2, const bf16* Bt2, const float* bias2, bf16* out2, int N2, int gn2,
    int K) {
  __shared__ short As[2][128 * 64];
  __shared__ short Bs[2][128 * 64];
  int t = threadIdx.x, lane = t & 63, wv = t >> 6;
  int bid = blockIdx.x;
  const bf16 *Asrc, *Btsrc; const float* bias; bf16* outB; int N, gn, nwg;
  if (bid < nwg1) {
    Asrc = A1; Btsrc = Bt1; bias = bias1; outB = out1; N = N1; gn = gn1; nwg = nwg1;
  } else {
    bid -= nwg1;
    Asrc = A2; Btsrc = Bt2; bias = bias2; outB = out2; N = N2; gn = gn2;
    nwg = gridDim.x - nwg1;
  }
  int cpx = nwg >> 3;
  int swz = (bid & 7) * cpx + (bid >> 3);
  int by = swz / gn, bx = swz % gn;
  int m0 = by << 7, n0 = bx << 7;
  f32x4 acc[4][4] = {};
  int mo_l = (wv >> 1) << 6, no_l = (wv & 1) << 6;

  int srow[4], scol[4];
#pragma unroll
  for (int j = 0; j < 4; ++j) {
    srow[j] = wv * 32 + j * 8 + (lane >> 3);
    scol[j] = ((lane & 7) ^ (srow[j] & 7)) << 3;
  }
  const short* Ap = (const short*)Asrc;
  const short* Bp = (const short*)Btsrc;

  int koff = lane >> 4;
  int rowA[4], rowB[4];
#pragma unroll
  for (int i = 0; i < 4; ++i) {
    rowA[i] = mo_l + i * 16 + (lane & 15);
    rowB[i] = no_l + i * 16 + (lane & 15);
  }

  auto stage = [&](int bufI, int kk) {
#pragma unroll
    for (int j = 0; j < 4; ++j) {
      gload16(Ap + (size_t)(m0 + srow[j]) * K + kk + scol[j],
              &As[bufI][(wv * 32 + j * 8) * 64]);
      gload16(Bp + (size_t)(n0 + srow[j]) * K + kk + scol[j],
              &Bs[bufI][(wv * 32 + j * 8) * 64]);
    }
  };

  stage(0, 0);
  __syncthreads();
  int cur = 0;
  for (int kk = 0; kk < K; kk += 64) {
    int nxt = cur ^ 1;
    if (kk + 64 < K) stage(nxt, kk + 64);
    short8_t af[2][4], bfv[2][4];
#pragma unroll
    for (int h = 0; h < 2; ++h)
#pragma unroll
      for (int i = 0; i < 4; ++i) {
        int cA = ((h * 4 + koff) ^ (rowA[i] & 7)) << 3;
        af[h][i] = *(const short8_t*)&As[cur][rowA[i] * 64 + cA];
        int cB = ((h * 4 + koff) ^ (rowB[i] & 7)) << 3;
        bfv[h][i] = *(const short8_t*)&Bs[cur][rowB[i] * 64 + cB];
      }
#pragma unroll
    for (int h = 0; h < 2; ++h)
#pragma unroll
      for (int mt = 0; mt < 4; ++mt)
#pragma unroll
        for (int nt = 0; nt < 4; ++nt)
          acc[mt][nt] = __builtin_amdgcn_mfma_f32_16x16x32_bf16(af[h][mt], bfv[h][nt], acc[mt][nt], 0, 0, 0);
    __syncthreads();
    cur = nxt;
  }

  int mo = m0 + mo_l, no = n0 + no_l;
#pragma unroll
  for (int mt = 0; mt < 4; ++mt)
#pragma unroll
    for (int nt = 0; nt < 4; ++nt) {
      int n = no + nt * 16 + (lane & 15);
      float bia = bias[n];
#pragma unroll
      for (int r = 0; r < 4; ++r) {
        int m = mo + mt * 16 + (lane >> 4) * 4 + r;
        ((short*)outB)[(size_t)m * N + n] = f2bf(acc[mt][nt][r] + bia);
      }
    }
}

// Flash attention v5 (R13-proven): XCD swizzle, T14 async stage, defer-max,
// swizzled V^T, packed-dword P, log2 softmax, setprio.
__global__ __launch_bounds__(512) void attn_kernel(
    const bf16* __restrict__ q, const bf16* __restrict__ k,
    const bf16* __restrict__ v, bf16* __restrict__ y,
    int QL, int KVL, int qs, int ks, int vs, float scl) {
  __shared__ short Kt[64 * 136];
  __shared__ short Vt[128 * 72];
  __shared__ unsigned Pl[128 * 36];
  __shared__ float rl[8 * 16];
  __shared__ float ll[8 * 16];
  int t = threadIdx.x, lane = t & 63, wv = t >> 6;
  int l15 = lane & 15, koff = lane >> 4;
  int id = blockIdx.x;
  int c = id & 7, j = id >> 3;
  int bh = c * 4 + (j >> 4);
  int qx = j & 15;
  int b = bh / NHEADS, h = bh % NHEADS;
  int q0 = qx * 128 + wv * 16;
  const short* qp = (const short*)q;
  const short* kp = (const short*)k;
  const short* vp = (const short*)v;
  const float c1 = scl * 1.44269504088896f;
  short8_t qf[4];
  {
    size_t qbase = ((size_t)(b * QL) + q0 + l15) * qs + h * HDIM + koff * 8;
#pragma unroll
    for (int kc = 0; kc < 4; ++kc) qf[kc] = *(const short8_t*)(qp + qbase + kc * 32);
  }
  f32x4 o[8] = {};
  float m_run = -1e30f, l_run = 0.f;
  int strow = t >> 3, stcol = (t & 7) * 16;
  size_t kbase = (size_t)(b * KVL + strow) * ks + h * HDIM + stcol;
  size_t vbase = (size_t)(b * KVL + strow) * vs + h * HDIM + stcol;
  short8_t kreg[2], vreg[2];
  kreg[0] = *(const short8_t*)(kp + kbase);
  kreg[1] = *(const short8_t*)(kp + kbase + 8);
  vreg[0] = *(const short8_t*)(vp + vbase);
  vreg[1] = *(const short8_t*)(vp + vbase + 8);
  for (int kt0 = 0; kt0 < KVL; kt0 += 64) {
#pragma unroll
    for (int cc = 0; cc < 2; ++cc)
      *(short8_t*)&Kt[strow * 136 + stcol + cc * 8] = kreg[cc];
#pragma unroll
    for (int cc = 0; cc < 2; ++cc) {
#pragma unroll
      for (int e = 0; e < 8; ++e) {
        int d = stcol + cc * 8 + e;
        Vt[d * 72 + (strow ^ ((d >> 2) & 0x38))] = vreg[cc][e];
      }
    }
    if (kt0 + 64 < KVL) {
      size_t kb2 = kbase + (size_t)(kt0 + 64) * ks;
      size_t vb2 = vbase + (size_t)(kt0 + 64) * vs;
      kreg[0] = *(const short8_t*)(kp + kb2);
      kreg[1] = *(const short8_t*)(kp + kb2 + 8);
      vreg[0] = *(const short8_t*)(vp + vb2);
      vreg[1] = *(const short8_t*)(vp + vb2 + 8);
    }
    __syncthreads();
    f32x4 st[4];
    SETPRIO(1);
#pragma unroll
    for (int kt = 0; kt < 4; ++kt) {
      f32x4 aa = {0.f, 0.f, 0.f, 0.f};
#pragma unroll
      for (int kc = 0; kc < 4; ++kc) {
        short8_t kf = *(const short8_t*)&Kt[(kt * 16 + l15) * 136 + kc * 32 + koff * 8];
        aa = __builtin_amdgcn_mfma_f32_16x16x32_bf16(kf, qf[kc], aa, 0, 0, 0);
      }
      st[kt] = aa;
    }
    SETPRIO(0);
    float mk[4];
#pragma unroll
    for (int kt = 0; kt < 4; ++kt)
      mk[kt] = fmaxf(fmaxf(st[kt][0], st[kt][1]), fmaxf(st[kt][2], st[kt][3]));
    float mt_ = fmaxf(fmaxf(mk[0], mk[1]), fmaxf(mk[2], mk[3]));
    mt_ = fmaxf(mt_, __shfl_xor(mt_, 16, 64));
    mt_ = fmaxf(mt_, __shfl_xor(mt_, 32, 64));
    float mtc = mt_ * c1;
    bool nos = __all(mtc <= m_run + 8.0f);
    float m_new = nos ? m_run : fmaxf(m_run, mtc);
    float pk[4];
#pragma unroll
    for (int kt = 0; kt < 4; ++kt) {
#pragma unroll
      for (int r = 0; r < 4; ++r)
        st[kt][r] = exp2f(fmaf(st[kt][r], c1, -m_new));
      pk[kt] = (st[kt][0] + st[kt][1]) + (st[kt][2] + st[kt][3]);
    }
    float ps = (pk[0] + pk[1]) + (pk[2] + pk[3]);
    ps += __shfl_xor(ps, 16, 64);
    ps += __shfl_xor(ps, 32, 64);
    if (!nos) {
      float rfac = exp2f(m_run - m_new);
      l_run = l_run * rfac + ps;
      m_run = m_new;
      if (lane < 16) rl[wv * 16 + lane] = rfac;
      float rr[4];
#pragma unroll
      for (int r = 0; r < 4; ++r) rr[r] = rl[wv * 16 + koff * 4 + r];
#pragma unroll
      for (int dt = 0; dt < 8; ++dt)
#pragma unroll
        for (int r = 0; r < 4; ++r) o[dt][r] *= rr[r];
    } else {
      l_run += ps;
    }
#pragma unroll
    for (int kt = 0; kt < 4; ++kt)
#pragma unroll
      for (int rp = 0; rp < 2; ++rp) {
        unsigned lo = (unsigned short)f2bf(st[kt][2 * rp]);
        unsigned hi = (unsigned short)f2bf(st[kt][2 * rp + 1]);
        Pl[(wv * 16 + l15) * 36 + kt * 8 + koff * 2 + rp] = lo | (hi << 16);
      }
    SETPRIO(1);
#pragma unroll
    for (int kc2 = 0; kc2 < 2; ++kc2) {
      short8_t pa = *(const short8_t*)&Pl[(wv * 16 + l15) * 36 + kc2 * 16 + koff * 4];
#pragma unroll
      for (int dt = 0; dt < 8; ++dt) {
        int drow = dt * 16 + l15;
        int kv0 = (kc2 * 32 + koff * 8) ^ ((drow >> 2) & 0x38);
        short8_t vf = *(const short8_t*)&Vt[drow * 72 + kv0];
        o[dt] = __builtin_amdgcn_mfma_f32_16x16x32_bf16(pa, vf, o[dt], 0, 0, 0);
      }
    }
    SETPRIO(0);
    __syncthreads();
  }
  if (lane < 16) ll[wv * 16 + lane] = 1.f / l_run;
  float li[4];
#pragma unroll
  for (int r = 0; r < 4; ++r) li[r] = ll[wv * 16 + koff * 4 + r];
  short* yp = (short*)y;
#pragma unroll
  for (int dt = 0; dt < 8; ++dt)
#pragma unroll
    for (int r = 0; r < 4; ++r) {
      int qq = q0 + koff * 4 + r;
      int d = dt * 16 + l15;
      yp[((size_t)(b * QL) + qq) * DIMX + h * HDIM + d] = f2bf(o[dt][r] * li[r]);
    }
}

// ws layout (bytes)
#define OFF_EM    0ull
#define OFF_BQKV  (512ull << 10)
#define OFF_BCKV  (560ull << 10)
#define OFF_XN    (1ull << 20)
#define OFF_QKB   (17ull << 20)   // fused qk: 32 MB (17..49)
#define OFF_VB2   (49ull << 20)   // self-attn v: 16 MB (49..65)
#define OFF_CAQ   (17ull << 20)
#define OFF_KV    (33ull << 20)
#define OFF_QB    (65ull << 20)
#define OFF_KB    (81ull << 20)
#define OFF_YB    (97ull << 20)
#define OFF_CTX   (113ull << 20)
#define OFF_WBUF  (117ull << 20)
#define OFF_HB    (17ull << 20)   // FFN hidden 64 MB (17..81)
#define OFF_PS    (81ull << 20)   // FFN2 partials 2x16 MB (81..113)

extern "C" void kernel_launch(void* const* d_in, const int* in_sizes, int n_in,
                              void* d_out, int out_size, void* d_ws, size_t ws_size,
                              hipStream_t stream) {
  const float* x       = (const float*)d_in[0];
  const float* e       = (const float*)d_in[1];
  const float* context = (const float*)d_in[2];
  const float* fcos    = (const float*)d_in[3];
  const float* fsin    = (const float*)d_in[4];
  const float* modu    = (const float*)d_in[5];
  const float* sa_wq = (const float*)d_in[6];  const float* sa_bq = (const float*)d_in[7];
  const float* sa_wk = (const float*)d_in[8];  const float* sa_bk = (const float*)d_in[9];
  const float* sa_wv = (const float*)d_in[10]; const float* sa_bv = (const float*)d_in[11];
  const float* sa_wo = (const float*)d_in[12]; const float* sa_bo = (const float*)d_in[13];
  const float* sa_nq = (const float*)d_in[14]; const float* sa_nk = (const float*)d_in[15];
  const float* ca_wq = (const float*)d_in[16]; const float* ca_bq = (const float*)d_in[17];
  const float* ca_wk = (const float*)d_in[18]; const float* ca_bk = (const float*)d_in[19];
  const float* ca_wv = (const float*)d_in[20]; const float* ca_bv = (const float*)d_in[21];
  const float* ca_wo = (const float*)d_in[22]; const float* ca_bo = (const float*)d_in[23];
  const float* ca_nq = (const float*)d_in[24]; const float* ca_nk = (const float*)d_in[25];
  const float* n3_w  = (const float*)d_in[26]; const float* n3_b  = (const float*)d_in[27];
  const float* f_w1  = (const float*)d_in[28]; const float* f_b1  = (const float*)d_in[29];
  const float* f_w2  = (const float*)d_in[30]; const float* f_b2  = (const float*)d_in[31];

  char* ws = (char*)d_ws;
  float* em   = (float*)(ws + OFF_EM);
  float* bqkv = (float*)(ws + OFF_BQKV);
  float* bckv = (float*)(ws + OFF_BCKV);
  bf16* xn    = (bf16*)(ws + OFF_XN);
  bf16* qkb   = (bf16*)(ws + OFF_QKB);
  bf16* vb2   = (bf16*)(ws + OFF_VB2);
  bf16* caqb  = (bf16*)(ws + OFF_CAQ);
  bf16* kvb   = (bf16*)(ws + OFF_KV);
  bf16* qb    = (bf16*)(ws + OFF_QB);
  bf16* kb    = (bf16*)(ws + OFF_KB);
  bf16* yb    = (bf16*)(ws + OFF_YB);
  bf16* ctxb  = (bf16*)(ws + OFF_CTX);
  bf16* wbuf  = (bf16*)(ws + OFF_WBUF);
  bf16* hb    = (bf16*)(ws + OFF_HB);
  bf16* ps    = (bf16*)(ws + OFF_PS);
  float* xw   = (float*)d_out;

  const int M = BSZ * SLEN;
  const int MC = BSZ * CTXL;
  const float scl = 0.08838834764831845f;
  const size_t WSTRIDE = (size_t)DIMX * DIMX;

#define GEMM256(Am, Bt, Md, Nd, Kd, bias, oF, oB, res, sc, scs, rpb, mode) \
  gemm256<<<((Md) / 256) * ((Nd) / 256), 512, 0, stream>>>(Am, Bt, bias, oF, oB, res, sc, \
                                                           scs, rpb, (Nd) / 256, Nd, Kd, Kd, 1, 0ll, mode)
#define GEMM128(Am, Bt, Md, Nd, Kd, bias, oF, oB, res, sc, scs, rpb, mode) \
  gemm_bt<<<((Md) / 128) * ((Nd) / 128), 256, 0, stream>>>(Am, Bt, bias, oF, oB, res, sc, scs, rpb, (Nd) / 128, Nd, Kd, mode)

  prep_kernel<<<(BSZ * 6 * DIMX + 5 * DIMX + MC * DIMX / 8 + 255) / 256, 256, 0, stream>>>(
      e, modu, em, sa_bq, sa_bk, sa_bv, bqkv, ca_bk, ca_bv, bckv, context, ctxb);

  // --- self attention ---
  ln_kernel<<<M, 256, 0, stream>>>(x, em + 1 * DIMX, em + 0 * DIMX, 6 * DIMX, 1.0f, SLEN, xn);

  transpose_w4<<<dim3(DIMX / 64, DIMX / 64, 4), 256, 0, stream>>>(
      sa_wq, sa_wk, sa_wv, sa_wo, wbuf, DIMX, DIMX);

  // fused QK: N=4096 -> 256 blocks (1 exact round); V: 512 blocks (2 rounds)
  GEMM256(xn, wbuf, M, 2 * DIMX, DIMX, bqkv, nullptr, qkb, nullptr, nullptr, 0, 1, 1);
  GEMM128(xn, wbuf + 2 * WSTRIDE, M, DIMX, DIMX, sa_bv, nullptr, vb2, nullptr, nullptr, 0, 1, 1);

  rms_rope_kernel<<<dim3(M, 2), 256, 0, stream>>>(qkb, 2 * DIMX, sa_nq, sa_nk,
                                                  fcos, fsin, 1, qb, kb);

  attn_kernel<<<512, 512, 0, stream>>>(qb, kb, vb2, yb, SLEN, SLEN, DIMX, DIMX, DIMX, scl);

  GEMM128(yb, wbuf + 3 * WSTRIDE, M, DIMX, DIMX, sa_bo, xw, nullptr,
          x, em + 2 * DIMX, 6 * DIMX, SLEN, 3);

  // --- cross attention ---
  ln_kernel<<<M, 256, 0, stream>>>(xw, n3_w, n3_b, 0, 0.0f, SLEN, xn);

  transpose_w4<<<dim3(DIMX / 64, DIMX / 64, 4), 256, 0, stream>>>(
      ca_wq, ca_wk, ca_wv, ca_wo, wbuf, DIMX, DIMX);

  // merged ca_q (512 blocks) + ca_kv (256 blocks): 768 = 1.5 residency rounds
  gemm_bt_dual<<<768, 256, 0, stream>>>(
      xn, wbuf, ca_bq, caqb, DIMX, DIMX / 128, 512,
      ctxb, wbuf + WSTRIDE, bckv, kvb, 2 * DIMX, 2 * DIMX / 128,
      DIMX);

  rms_mix_kernel<<<M + MC, 256, 0, stream>>>(caqb, ca_nq, qb, kvb, ca_nk, kb, M);

  attn_kernel<<<512, 512, 0, stream>>>(qb, kb, (bf16*)((short*)kvb + DIMX), yb,
                                       SLEN, CTXL, DIMX, DIMX, 2 * DIMX, scl);

  GEMM128(yb, wbuf + 3 * WSTRIDE, M, DIMX, DIMX, ca_bo, xw, nullptr,
          xw, nullptr, 0, SLEN, 3);

  // --- FFN ---
  ln_kernel<<<M, 256, 0, stream>>>(xw, em + 4 * DIMX, em + 3 * DIMX, 6 * DIMX, 1.0f, SLEN, xn);

  transpose_w4<<<dim3(FFND / 64, DIMX / 64, 1), 256, 0, stream>>>(
      f_w1, nullptr, nullptr, nullptr, wbuf, DIMX, FFND);
  GEMM256(xn, wbuf, M, FFND, DIMX, f_b1, nullptr, hb, nullptr, nullptr, 0, 1, 2);

  transpose_w4<<<dim3(DIMX / 64, FFND / 64, 1), 256, 0, stream>>>(
      f_w2, nullptr, nullptr, nullptr, wbuf, FFND, DIMX);
  gemm256<<<2 * (M / 256) * (DIMX / 256), 512, 0, stream>>>(
      hb, wbuf, f_b2, nullptr, ps, nullptr, nullptr, 0, 1, DIMX / 256, DIMX,
      FFND, FFND / 2, 2, (long long)M * DIMX, 5);
  combine_kernel<<<M * DIMX / 8 / 256, 256, 0, stream>>>(
      ps, ps + (size_t)M * DIMX, f_b2, xw, em + 5 * DIMX, 6 * DIMX, SLEN, xw, DIMX);
}